// Round 1
// baseline (686.077 us; speedup 1.0000x reference)
//
#include <hip/hip_runtime.h>
#include <math.h>

// Match reference fp32 arithmetic: no FMA contraction anywhere in this file.
#pragma clang fp contract(off)

#define NPTS 2048
#define KNN 10
#define NOUT 256

// ---------------- LAPACK-faithful fp32 helpers ----------------

__device__ __forceinline__ float lapy2f(float x, float y) {
  // SLAPY2: sqrt(x^2+y^2) with scaling, exact op order
  float xa = fabsf(x), ya = fabsf(y);
  float w = fmaxf(xa, ya), z = fminf(xa, ya);
  if (z == 0.f) return w;
  float t = z / w;
  return w * sqrtf(1.f + t * t);
}

// SLARTG, LAPACK >= 3.10 convention (modern OpenBLAS / numpy wheels).
#define SLARTG_NEW 1
__device__ __forceinline__ void slartgf(float f, float g, float& c, float& s, float& r) {
#if SLARTG_NEW
  if (g == 0.f) { c = 1.f; s = 0.f; r = f; }
  else if (f == 0.f) { c = 0.f; s = copysignf(1.f, g); r = fabsf(g); }
  else {
    float d = sqrtf(f * f + g * g);
    float p = 1.f / d;
    c = fabsf(f) * p;
    s = g * copysignf(p, f);
    r = copysignf(d, f);
  }
#else
  if (g == 0.f) { c = 1.f; s = 0.f; r = f; }
  else if (f == 0.f) { c = 0.f; s = 1.f; r = g; }
  else {
    r = sqrtf(f * f + g * g);
    c = f / r;
    s = g / r;
    if (fabsf(f) > fabsf(g) && c < 0.f) { c = -c; s = -s; r = -r; }
  }
#endif
}

__device__ void slaev2f(float a, float b, float c,
                        float& rt1, float& rt2, float& cs1, float& sn1) {
  float sm = a + c;
  float df = a - c;
  float adf = fabsf(df);
  float tb = b + b;
  float ab = fabsf(tb);
  float acmx, acmn;
  if (fabsf(a) > fabsf(c)) { acmx = a; acmn = c; } else { acmx = c; acmn = a; }
  float rt;
  if (adf > ab)      { float t = ab / adf; rt = adf * sqrtf(1.f + t * t); }
  else if (adf < ab) { float t = adf / ab; rt = ab * sqrtf(1.f + t * t); }
  else               { rt = ab * sqrtf(2.f); }
  int sgn1;
  if (sm < 0.f) {
    rt1 = 0.5f * (sm - rt); sgn1 = -1;
    rt2 = (acmx / rt1) * acmn - (b / rt1) * b;
  } else if (sm > 0.f) {
    rt1 = 0.5f * (sm + rt); sgn1 = 1;
    rt2 = (acmx / rt1) * acmn - (b / rt1) * b;
  } else {
    rt1 = 0.5f * rt; rt2 = -0.5f * rt; sgn1 = 1;
  }
  int sgn2; float cs;
  if (df >= 0.f) { cs = df + rt; sgn2 = 1; } else { cs = df - rt; sgn2 = -1; }
  float acs = fabsf(cs);
  if (acs > ab) {
    float ct = -tb / cs;
    sn1 = 1.f / sqrtf(1.f + ct * ct);
    cs1 = ct * sn1;
  } else {
    if (ab == 0.f) { cs1 = 1.f; sn1 = 0.f; }
    else {
      float tn = -cs / tb;
      cs1 = 1.f / sqrtf(1.f + tn * tn);
      sn1 = tn * cs1;
    }
  }
  if (sgn1 == sgn2) { float tn = cs1; cs1 = -sn1; sn1 = tn; }
}

__device__ __forceinline__ void rot_cols(float z[3][3], int j1, int j2, float c, float s) {
  // DLASR body, columns j1,j2 are 1-indexed
  for (int i = 0; i < 3; ++i) {
    float temp = z[i][j2 - 1];
    z[i][j2 - 1] = c * temp - s * z[i][j1 - 1];
    z[i][j1 - 1] = s * temp + c * z[i][j1 - 1];
  }
}

// SSTEQR('I', n=3) faithful port. dd[3], ee[2], z init to identity.
__device__ void ssteqr3(float* dd, float* ee, float z[3][3]) {
  const float eps = 5.9604645e-8f;       // slamch('E') = 2^-24
  const float eps2 = eps * eps;
  const float safmin = 1.1754944e-38f;   // slamch('S')
  const int n = 3, nm1 = 2;
  const int nmaxit = 90;
  int jtot = 0;
  float wc[2], wsn[2];
  int l1 = 1;
  for (int og = 0; og < 64; ++og) {
    if (l1 > n) break;
    if (l1 > 1) ee[l1 - 2] = 0.f;
    int m = n;
    if (l1 <= nm1) {
      for (int mm = l1; mm <= nm1; ++mm) {
        float tst = fabsf(ee[mm - 1]);
        if (tst == 0.f) { m = mm; break; }
        if (tst <= (sqrtf(fabsf(dd[mm - 1])) * sqrtf(fabsf(dd[mm]))) * eps) {
          ee[mm - 1] = 0.f; m = mm; break;
        }
      }
    }
    int l = l1, lend = m;
    l1 = m + 1;
    if (lend == l) continue;
    // (block scaling skipped: anorm is well inside [ssfmin, ssfmax] for this data)
    if (fabsf(dd[lend - 1]) < fabsf(dd[l - 1])) { int t = lend; lend = l; l = t; }
    if (lend > l) {
      // ---- QL iteration ----
      for (int it = 0; it < 256; ++it) {
        int m2 = lend;
        if (l != lend) {
          for (int mm = l; mm <= lend - 1; ++mm) {
            float tst = ee[mm - 1] * ee[mm - 1];
            if (tst <= (eps2 * fabsf(dd[mm - 1])) * fabsf(dd[mm]) + safmin) { m2 = mm; break; }
          }
        }
        if (m2 < lend) ee[m2 - 1] = 0.f;
        float p = dd[l - 1];
        if (m2 == l) {
          dd[l - 1] = p;
          l += 1;
          if (l <= lend) continue;
          break;
        }
        if (m2 == l + 1) {
          float rt1, rt2, c, s;
          slaev2f(dd[l - 1], ee[l - 1], dd[l], rt1, rt2, c, s);
          rot_cols(z, l, l + 1, c, s);
          dd[l - 1] = rt1; dd[l] = rt2; ee[l - 1] = 0.f;
          l += 2;
          if (l <= lend) continue;
          break;
        }
        if (jtot == nmaxit) break;
        jtot++;
        float g = (dd[l] - p) / (2.f * ee[l - 1]);
        float r = lapy2f(g, 1.f);
        g = dd[m2 - 1] - p + ee[l - 1] / (g + copysignf(r, g));
        float s = 1.f, c = 1.f;
        p = 0.f;
        for (int i = m2 - 1; i >= l; --i) {
          float f = s * ee[i - 1];
          float bb = c * ee[i - 1];
          slartgf(g, f, c, s, r);
          if (i != m2 - 1) ee[i] = r;
          g = dd[i] - p;
          r = (dd[i - 1] - g) * s + 2.f * c * bb;
          p = s * r;
          dd[i] = g + p;
          g = c * r - bb;
          wc[i - 1] = c;
          wsn[i - 1] = -s;
        }
        int mm = m2 - l + 1;
        for (int j = mm - 1; j >= 1; --j)
          rot_cols(z, l + j - 1, l + j, wc[l + j - 2], wsn[l + j - 2]);
        dd[l - 1] = dd[l - 1] - p;
        ee[l - 1] = g;
      }
    } else {
      // ---- QR iteration ----
      for (int it = 0; it < 256; ++it) {
        int m2 = lend;
        if (l != lend) {
          for (int mm = l; mm >= lend + 1; --mm) {
            float tst = ee[mm - 2] * ee[mm - 2];
            if (tst <= (eps2 * fabsf(dd[mm - 1])) * fabsf(dd[mm - 2]) + safmin) { m2 = mm; break; }
          }
        }
        if (m2 > lend) ee[m2 - 2] = 0.f;
        float p = dd[l - 1];
        if (m2 == l) {
          dd[l - 1] = p;
          l -= 1;
          if (l >= lend) continue;
          break;
        }
        if (m2 == l - 1) {
          float rt1, rt2, c, s;
          slaev2f(dd[l - 2], ee[l - 2], dd[l - 1], rt1, rt2, c, s);
          rot_cols(z, l - 1, l, c, s);
          dd[l - 2] = rt1; dd[l - 1] = rt2; ee[l - 2] = 0.f;
          l -= 2;
          if (l >= lend) continue;
          break;
        }
        if (jtot == nmaxit) break;
        jtot++;
        float g = (dd[l - 2] - p) / (2.f * ee[l - 2]);
        float r = lapy2f(g, 1.f);
        g = dd[m2 - 1] - p + ee[l - 2] / (g + copysignf(r, g));
        float s = 1.f, c = 1.f;
        p = 0.f;
        for (int i = m2; i <= l - 1; ++i) {
          float f = s * ee[i - 1];
          float bb = c * ee[i - 1];
          slartgf(g, f, c, s, r);
          if (i != m2) ee[i - 2] = r;
          g = dd[i - 1] - p;
          r = (dd[i] - g) * s + 2.f * c * bb;
          p = s * r;
          dd[i - 1] = g + p;
          g = c * r - bb;
          wc[i - 1] = c;
          wsn[i - 1] = s;
        }
        int mm = l - m2 + 1;
        for (int j = 1; j <= mm - 1; ++j)
          rot_cols(z, m2 + j - 1, m2 + j, wc[m2 + j - 2], wsn[m2 + j - 2]);
        dd[l - 1] = dd[l - 1] - p;
        ee[l - 2] = g;
      }
    }
  }
  // ascending selection sort with column swaps (DSTEQR label 160)
  for (int ii = 2; ii <= n; ++ii) {
    int i = ii - 1, k = i;
    float p = dd[i - 1];
    for (int j = ii; j <= n; ++j) {
      if (dd[j - 1] < p) { k = j; p = dd[j - 1]; }
    }
    if (k != i) {
      dd[k - 1] = dd[i - 1]; dd[i - 1] = p;
      for (int r0 = 0; r0 < 3; ++r0) {
        float t = z[r0][i - 1]; z[r0][i - 1] = z[r0][k - 1]; z[r0][k - 1] = t;
      }
    }
  }
}

// ---------------- Kernel 1: KNN + covariance + eigh(normal) ----------------

__global__ __launch_bounds__(256) void knn_normals_kernel(const float* __restrict__ pts,
                                                          float* __restrict__ nrm) {
  __shared__ float sp[NPTS * 3];
  for (int t = threadIdx.x; t < NPTS * 3; t += 256) sp[t] = pts[t];
  __syncthreads();
  int i = blockIdx.x * 256 + threadIdx.x;
  if (i >= NPTS) return;
  float px = sp[3 * i], py = sp[3 * i + 1], pz = sp[3 * i + 2];

  // top-(K+1) smallest squared distances, ties -> lower index (jax top_k semantics)
  float nd[KNN + 1];
  int nidx[KNN + 1];
#pragma unroll
  for (int t = 0; t <= KNN; ++t) { nd[t] = 3.402823466e38f; nidx[t] = 0; }
  for (int j = 0; j < NPTS; ++j) {
    float dx = px - sp[3 * j];
    float dy = py - sp[3 * j + 1];
    float dz = pz - sp[3 * j + 2];
    float sq = dx * dx;
    sq = sq + dy * dy;
    sq = sq + dz * dz;
    if (sq < nd[KNN]) {
      int t = KNN;
      while (t > 0 && sq < nd[t - 1]) {
        nd[t] = nd[t - 1]; nidx[t] = nidx[t - 1]; --t;
      }
      nd[t] = sq; nidx[t] = j;
    }
  }

  // neighbors are entries 1..10 (entry 0 is self, distance 0); same order as top_k
  float nx[KNN], ny[KNN], nz[KNN];
  float sx = 0.f, sy = 0.f, sz = 0.f;
  for (int t = 0; t < KNN; ++t) {
    int j = nidx[t + 1];
    nx[t] = sp[3 * j]; ny[t] = sp[3 * j + 1]; nz[t] = sp[3 * j + 2];
    sx = sx + nx[t]; sy = sy + ny[t]; sz = sz + nz[t];
  }
  float mx = sx / 10.f, my = sy / 10.f, mz = sz / 10.f;
  float a11 = 0.f, a21 = 0.f, a31 = 0.f, a22 = 0.f, a32 = 0.f, a33 = 0.f;
  for (int t = 0; t < KNN; ++t) {
    float cx = nx[t] - mx, cy = ny[t] - my, cz = nz[t] - mz;
    a11 = a11 + cx * cx;
    a21 = a21 + cy * cx;
    a31 = a31 + cz * cx;
    a22 = a22 + cy * cy;
    a32 = a32 + cz * cy;
    a33 = a33 + cz * cz;
  }
  a11 = a11 / 10.f; a21 = a21 / 10.f; a31 = a31 / 10.f;
  a22 = a22 / 10.f; a32 = a32 / 10.f; a33 = a33 / 10.f;

  // SSYTD2 (uplo='L', n=3): one Householder reflector
  float dd[3], ee[2], tau1 = 0.f, v2 = 0.f;
  {
    float alpha = a21;
    float xnorm = fabsf(a31);
    if (xnorm == 0.f) {
      tau1 = 0.f; v2 = 0.f;
      dd[0] = a11; dd[1] = a22; dd[2] = a33; ee[0] = alpha; ee[1] = a32;
    } else {
      float beta = -copysignf(lapy2f(alpha, xnorm), alpha);
      tau1 = (beta - alpha) / beta;
      v2 = a31 * (1.f / (alpha - beta));       // DSCAL: reciprocal then multiply
      // DSYMV (lower, n=2), exact reference op order:
      float y1 = tau1 * a22; y1 = y1 + tau1 * (a32 * v2);
      float y2 = tau1 * a32; y2 = y2 + (tau1 * v2) * a33;
      // DDOT
      float dotv = y1; dotv = dotv + y2 * v2;
      float ac = -0.5f * tau1 * dotv;
      // DAXPY
      y1 = y1 + ac;
      y2 = y2 + ac * v2;
      // DSYR2 alpha=-1, reference op order
      float t1 = -y1, t2 = -1.f;
      a22 = (a22 + t1) + y1 * t2;
      a32 = (a32 + v2 * t1) + y2 * t2;
      float t1b = -y2, t2b = -v2;
      a33 = (a33 + v2 * t1b) + y2 * t2b;
      dd[0] = a11; dd[1] = a22; dd[2] = a33; ee[0] = beta; ee[1] = a32;
    }
  }
  float z[3][3] = {{1.f, 0.f, 0.f}, {0.f, 1.f, 0.f}, {0.f, 0.f, 1.f}};
  ssteqr3(dd, ee, z);
  // DORMTR: apply H1 = I - tau*v*v^T to rows 2..3 of eigvec column 0
  if (tau1 != 0.f) {
    float w = tau1 * (z[1][0] + v2 * z[2][0]);
    z[1][0] = z[1][0] - w;
    z[2][0] = z[2][0] - v2 * w;
  }
  nrm[3 * i]     = z[0][0];
  nrm[3 * i + 1] = z[1][0];
  nrm[3 * i + 2] = z[2][0];
}

// ---------------- Kernel 2: PPF features + mean + head matmul ----------------

__device__ __forceinline__ float angle3(float ax, float ay, float az,
                                        float bx, float by, float bz) {
  float cx = ay * bz - az * by;
  float cy = az * bx - ax * bz;
  float cz = ax * by - ay * bx;
  float sq = cx * cx + cy * cy + cz * cz;
  float nrmc = (sq > 0.f) ? sqrtf(sq) : 0.f;
  float dot = ax * bx + ay * by + az * bz;
  return atan2f(nrmc, dot);
}

__global__ __launch_bounds__(256) void ppf_kernel(const float* __restrict__ pts,
                                                  const float* __restrict__ nrm,
                                                  const float* __restrict__ Wm,
                                                  const float* __restrict__ bias,
                                                  float* __restrict__ out) {
  int i = blockIdx.x;
  float px = pts[3 * i], py = pts[3 * i + 1], pz = pts[3 * i + 2];
  float ax = nrm[3 * i], ay = nrm[3 * i + 1], az = nrm[3 * i + 2];
  float s0 = 0.f, s1 = 0.f, s2 = 0.f, s3 = 0.f;
  for (int j = threadIdx.x; j < NPTS; j += 256) {
    float dx = px - pts[3 * j];
    float dy = py - pts[3 * j + 1];
    float dz = pz - pts[3 * j + 2];
    float bx = nrm[3 * j], by = nrm[3 * j + 1], bz = nrm[3 * j + 2];
    float sq = dx * dx + dy * dy + dz * dz;
    s0 += (sq > 0.f) ? sqrtf(sq) : 0.f;
    s1 += angle3(ax, ay, az, dx, dy, dz);
    s2 += angle3(bx, by, bz, dx, dy, dz);
    s3 += angle3(ax, ay, az, bx, by, bz);
  }
  __shared__ float red[4][256];
  int tid = threadIdx.x;
  red[0][tid] = s0; red[1][tid] = s1; red[2][tid] = s2; red[3][tid] = s3;
  __syncthreads();
  for (int off = 128; off > 0; off >>= 1) {
    if (tid < off) {
      red[0][tid] += red[0][tid + off];
      red[1][tid] += red[1][tid + off];
      red[2][tid] += red[2][tid + off];
      red[3][tid] += red[3][tid + off];
    }
    __syncthreads();
  }
  float f0 = red[0][0] / 2048.f;
  float f1 = red[1][0] / 2048.f;
  float f2 = red[2][0] / 2048.f;
  float f3 = red[3][0] / 2048.f;
  int o = tid;  // NOUT == blockDim.x == 256
  float w0 = Wm[4 * o], w1 = Wm[4 * o + 1], w2 = Wm[4 * o + 2], w3 = Wm[4 * o + 3];
  out[i * NOUT + o] = (((f0 * w0 + f1 * w1) + f2 * w2) + f3 * w3) + bias[o];
}

// ---------------- launcher ----------------

extern "C" void kernel_launch(void* const* d_in, const int* in_sizes, int n_in,
                              void* d_out, int out_size, void* d_ws, size_t ws_size,
                              hipStream_t stream) {
  const float* pts = (const float*)d_in[0];   // (1,2048,3) fp32
  const float* Wm  = (const float*)d_in[1];   // (256,4) fp32
  const float* bs  = (const float*)d_in[2];   // (256,) fp32
  float* out = (float*)d_out;                 // (1,2048,256) fp32
  float* nrm = (float*)d_ws;                  // 2048*3 floats scratch

  knn_normals_kernel<<<NPTS / 256, 256, 0, stream>>>(pts, nrm);
  ppf_kernel<<<NPTS, 256, 0, stream>>>(pts, nrm, Wm, bs, out);
}

// Round 2
// 135.797 us; speedup vs baseline: 5.0522x; 5.0522x over previous
//
#include <hip/hip_runtime.h>
#include <math.h>

// Match reference fp32 arithmetic: no FMA contraction anywhere in this file.
#pragma clang fp contract(off)

#define NPTS 2048
#define KNN 10
#define NOUT 256

// ---------------- LAPACK-faithful fp32 helpers ----------------

__device__ __forceinline__ float lapy2f(float x, float y) {
  float xa = fabsf(x), ya = fabsf(y);
  float w = fmaxf(xa, ya), z = fminf(xa, ya);
  if (z == 0.f) return w;
  float t = z / w;
  return w * sqrtf(1.f + t * t);
}

// SLARTG, LAPACK >= 3.10 convention (modern OpenBLAS / numpy wheels).
__device__ __forceinline__ void slartgf(float f, float g, float& c, float& s, float& r) {
  if (g == 0.f) { c = 1.f; s = 0.f; r = f; }
  else if (f == 0.f) { c = 0.f; s = copysignf(1.f, g); r = fabsf(g); }
  else {
    float d = sqrtf(f * f + g * g);
    float p = 1.f / d;
    c = fabsf(f) * p;
    s = g * copysignf(p, f);
    r = copysignf(d, f);
  }
}

__device__ void slaev2f(float a, float b, float c,
                        float& rt1, float& rt2, float& cs1, float& sn1) {
  float sm = a + c;
  float df = a - c;
  float adf = fabsf(df);
  float tb = b + b;
  float ab = fabsf(tb);
  float acmx, acmn;
  if (fabsf(a) > fabsf(c)) { acmx = a; acmn = c; } else { acmx = c; acmn = a; }
  float rt;
  if (adf > ab)      { float t = ab / adf; rt = adf * sqrtf(1.f + t * t); }
  else if (adf < ab) { float t = adf / ab; rt = ab * sqrtf(1.f + t * t); }
  else               { rt = ab * sqrtf(2.f); }
  int sgn1;
  if (sm < 0.f) {
    rt1 = 0.5f * (sm - rt); sgn1 = -1;
    rt2 = (acmx / rt1) * acmn - (b / rt1) * b;
  } else if (sm > 0.f) {
    rt1 = 0.5f * (sm + rt); sgn1 = 1;
    rt2 = (acmx / rt1) * acmn - (b / rt1) * b;
  } else {
    rt1 = 0.5f * rt; rt2 = -0.5f * rt; sgn1 = 1;
  }
  int sgn2; float cs;
  if (df >= 0.f) { cs = df + rt; sgn2 = 1; } else { cs = df - rt; sgn2 = -1; }
  float acs = fabsf(cs);
  if (acs > ab) {
    float ct = -tb / cs;
    sn1 = 1.f / sqrtf(1.f + ct * ct);
    cs1 = ct * sn1;
  } else {
    if (ab == 0.f) { cs1 = 1.f; sn1 = 0.f; }
    else {
      float tn = -cs / tb;
      cs1 = 1.f / sqrtf(1.f + tn * tn);
      sn1 = tn * cs1;
    }
  }
  if (sgn1 == sgn2) { float tn = cs1; cs1 = -sn1; sn1 = tn; }
}

__device__ __forceinline__ void rot_cols(float z[3][3], int j1, int j2, float c, float s) {
  for (int i = 0; i < 3; ++i) {
    float temp = z[i][j2 - 1];
    z[i][j2 - 1] = c * temp - s * z[i][j1 - 1];
    z[i][j1 - 1] = s * temp + c * z[i][j1 - 1];
  }
}

// SSTEQR('I', n=3) faithful port. dd[3], ee[2], z init to identity.
__device__ void ssteqr3(float* dd, float* ee, float z[3][3]) {
  const float eps = 5.9604645e-8f;
  const float eps2 = eps * eps;
  const float safmin = 1.1754944e-38f;
  const int n = 3, nm1 = 2;
  const int nmaxit = 90;
  int jtot = 0;
  float wc[2], wsn[2];
  int l1 = 1;
  for (int og = 0; og < 64; ++og) {
    if (l1 > n) break;
    if (l1 > 1) ee[l1 - 2] = 0.f;
    int m = n;
    if (l1 <= nm1) {
      for (int mm = l1; mm <= nm1; ++mm) {
        float tst = fabsf(ee[mm - 1]);
        if (tst == 0.f) { m = mm; break; }
        if (tst <= (sqrtf(fabsf(dd[mm - 1])) * sqrtf(fabsf(dd[mm]))) * eps) {
          ee[mm - 1] = 0.f; m = mm; break;
        }
      }
    }
    int l = l1, lend = m;
    l1 = m + 1;
    if (lend == l) continue;
    if (fabsf(dd[lend - 1]) < fabsf(dd[l - 1])) { int t = lend; lend = l; l = t; }
    if (lend > l) {
      for (int it = 0; it < 256; ++it) {
        int m2 = lend;
        if (l != lend) {
          for (int mm = l; mm <= lend - 1; ++mm) {
            float tst = ee[mm - 1] * ee[mm - 1];
            if (tst <= (eps2 * fabsf(dd[mm - 1])) * fabsf(dd[mm]) + safmin) { m2 = mm; break; }
          }
        }
        if (m2 < lend) ee[m2 - 1] = 0.f;
        float p = dd[l - 1];
        if (m2 == l) {
          dd[l - 1] = p;
          l += 1;
          if (l <= lend) continue;
          break;
        }
        if (m2 == l + 1) {
          float rt1, rt2, c, s;
          slaev2f(dd[l - 1], ee[l - 1], dd[l], rt1, rt2, c, s);
          rot_cols(z, l, l + 1, c, s);
          dd[l - 1] = rt1; dd[l] = rt2; ee[l - 1] = 0.f;
          l += 2;
          if (l <= lend) continue;
          break;
        }
        if (jtot == nmaxit) break;
        jtot++;
        float g = (dd[l] - p) / (2.f * ee[l - 1]);
        float r = lapy2f(g, 1.f);
        g = dd[m2 - 1] - p + ee[l - 1] / (g + copysignf(r, g));
        float s = 1.f, c = 1.f;
        p = 0.f;
        for (int i = m2 - 1; i >= l; --i) {
          float f = s * ee[i - 1];
          float bb = c * ee[i - 1];
          slartgf(g, f, c, s, r);
          if (i != m2 - 1) ee[i] = r;
          g = dd[i] - p;
          r = (dd[i - 1] - g) * s + 2.f * c * bb;
          p = s * r;
          dd[i] = g + p;
          g = c * r - bb;
          wc[i - 1] = c;
          wsn[i - 1] = -s;
        }
        int mm = m2 - l + 1;
        for (int j = mm - 1; j >= 1; --j)
          rot_cols(z, l + j - 1, l + j, wc[l + j - 2], wsn[l + j - 2]);
        dd[l - 1] = dd[l - 1] - p;
        ee[l - 1] = g;
      }
    } else {
      for (int it = 0; it < 256; ++it) {
        int m2 = lend;
        if (l != lend) {
          for (int mm = l; mm >= lend + 1; --mm) {
            float tst = ee[mm - 2] * ee[mm - 2];
            if (tst <= (eps2 * fabsf(dd[mm - 1])) * fabsf(dd[mm - 2]) + safmin) { m2 = mm; break; }
          }
        }
        if (m2 > lend) ee[m2 - 2] = 0.f;
        float p = dd[l - 1];
        if (m2 == l) {
          dd[l - 1] = p;
          l -= 1;
          if (l >= lend) continue;
          break;
        }
        if (m2 == l - 1) {
          float rt1, rt2, c, s;
          slaev2f(dd[l - 2], ee[l - 2], dd[l - 1], rt1, rt2, c, s);
          rot_cols(z, l - 1, l, c, s);
          dd[l - 2] = rt1; dd[l - 1] = rt2; ee[l - 2] = 0.f;
          l -= 2;
          if (l >= lend) continue;
          break;
        }
        if (jtot == nmaxit) break;
        jtot++;
        float g = (dd[l - 2] - p) / (2.f * ee[l - 2]);
        float r = lapy2f(g, 1.f);
        g = dd[m2 - 1] - p + ee[l - 2] / (g + copysignf(r, g));
        float s = 1.f, c = 1.f;
        p = 0.f;
        for (int i = m2; i <= l - 1; ++i) {
          float f = s * ee[i - 1];
          float bb = c * ee[i - 1];
          slartgf(g, f, c, s, r);
          if (i != m2) ee[i - 2] = r;
          g = dd[i - 1] - p;
          r = (dd[i] - g) * s + 2.f * c * bb;
          p = s * r;
          dd[i - 1] = g + p;
          g = c * r - bb;
          wc[i - 1] = c;
          wsn[i - 1] = s;
        }
        int mm = l - m2 + 1;
        for (int j = 1; j <= mm - 1; ++j)
          rot_cols(z, m2 + j - 1, m2 + j, wc[m2 + j - 2], wsn[m2 + j - 2]);
        dd[l - 1] = dd[l - 1] - p;
        ee[l - 2] = g;
      }
    }
  }
  for (int ii = 2; ii <= n; ++ii) {
    int i = ii - 1, k = i;
    float p = dd[i - 1];
    for (int j = ii; j <= n; ++j) {
      if (dd[j - 1] < p) { k = j; p = dd[j - 1]; }
    }
    if (k != i) {
      dd[k - 1] = dd[i - 1]; dd[i - 1] = p;
      for (int r0 = 0; r0 < 3; ++r0) {
        float t = z[r0][i - 1]; z[r0][i - 1] = z[r0][k - 1]; z[r0][k - 1] = t;
      }
    }
  }
}

// ---------------- Kernel 1: parallel KNN select (one block per point) ----------------
// Key = (float_bits(sq) << 32) | j : fp32 sq >= 0 so uint order == float order;
// index in low bits reproduces jax top_k's lower-index tie-break exactly.

__global__ __launch_bounds__(256) void knn_select_kernel(const float* __restrict__ pts,
                                                         int* __restrict__ knn) {
  const int i = blockIdx.x;
  const int tid = threadIdx.x;
  // query point: uniform across block -> scalar loads
  float px = pts[3 * i], py = pts[3 * i + 1], pz = pts[3 * i + 2];

  // 8 candidates per thread, contiguous chunk
  unsigned long long key[8];
#pragma unroll
  for (int jj = 0; jj < 8; ++jj) {
    int j = (tid << 3) + jj;
    float dx = px - pts[3 * j];
    float dy = py - pts[3 * j + 1];
    float dz = pz - pts[3 * j + 2];
    float sq = dx * dx;
    sq = sq + dy * dy;
    sq = sq + dz * dz;
    key[jj] = (((unsigned long long)__float_as_uint(sq)) << 32) | (unsigned int)j;
  }

  // branch-free sort of 8 keys: 19-comparator optimal network
#define CE(a, b)                                              \
  {                                                           \
    unsigned long long lo = key[a] < key[b] ? key[a] : key[b];\
    unsigned long long hi = key[a] < key[b] ? key[b] : key[a];\
    key[a] = lo; key[b] = hi;                                 \
  }
  CE(0, 1) CE(2, 3) CE(4, 5) CE(6, 7)
  CE(0, 2) CE(1, 3) CE(4, 6) CE(5, 7)
  CE(1, 2) CE(5, 6) CE(0, 4) CE(3, 7)
  CE(1, 5) CE(2, 6)
  CE(1, 4) CE(3, 6)
  CE(2, 4) CE(3, 5)
  CE(3, 4)
#undef CE

  __shared__ unsigned long long wmin[4];
  // 11 rounds: pop global min each round. Round 0 is self (sq=0), rounds 1..10
  // are the K neighbors in exact top_k order.
  for (int r = 0; r < KNN + 1; ++r) {
    unsigned long long k = key[0];
#pragma unroll
    for (int off = 32; off > 0; off >>= 1) {
      unsigned long long o = __shfl_xor(k, off, 64);
      k = (o < k) ? o : k;
    }
    if ((tid & 63) == 0) wmin[tid >> 6] = k;
    __syncthreads();
    unsigned long long g0 = wmin[0] < wmin[1] ? wmin[0] : wmin[1];
    unsigned long long g1 = wmin[2] < wmin[3] ? wmin[2] : wmin[3];
    unsigned long long g = g0 < g1 ? g0 : g1;
    if (r > 0 && tid == 0) knn[i * KNN + (r - 1)] = (int)(unsigned int)(g & 0xffffffffULL);
    if (key[0] == g) {
      // winner pops its head (unique: index bits make keys distinct)
#pragma unroll
      for (int q = 0; q < 7; ++q) key[q] = key[q + 1];
      key[7] = 0xFFFFFFFFFFFFFFFFULL;
    }
    __syncthreads();
  }
}

// ---------------- Kernel 2: covariance + eigh -> normals (one thread per point) ----------------

__global__ __launch_bounds__(256) void normals_kernel(const float* __restrict__ pts,
                                                      const int* __restrict__ knn,
                                                      float* __restrict__ nrm) {
  int i = blockIdx.x * 256 + threadIdx.x;
  if (i >= NPTS) return;

  float nx[KNN], ny[KNN], nz[KNN];
  float sx = 0.f, sy = 0.f, sz = 0.f;
  for (int t = 0; t < KNN; ++t) {
    int j = knn[i * KNN + t];
    nx[t] = pts[3 * j]; ny[t] = pts[3 * j + 1]; nz[t] = pts[3 * j + 2];
    sx = sx + nx[t]; sy = sy + ny[t]; sz = sz + nz[t];
  }
  float mx = sx / 10.f, my = sy / 10.f, mz = sz / 10.f;
  float a11 = 0.f, a21 = 0.f, a31 = 0.f, a22 = 0.f, a32 = 0.f, a33 = 0.f;
  for (int t = 0; t < KNN; ++t) {
    float cx = nx[t] - mx, cy = ny[t] - my, cz = nz[t] - mz;
    a11 = a11 + cx * cx;
    a21 = a21 + cy * cx;
    a31 = a31 + cz * cx;
    a22 = a22 + cy * cy;
    a32 = a32 + cz * cy;
    a33 = a33 + cz * cz;
  }
  a11 = a11 / 10.f; a21 = a21 / 10.f; a31 = a31 / 10.f;
  a22 = a22 / 10.f; a32 = a32 / 10.f; a33 = a33 / 10.f;

  // SSYTD2 (uplo='L', n=3): one Householder reflector
  float dd[3], ee[2], tau1 = 0.f, v2 = 0.f;
  {
    float alpha = a21;
    float xnorm = fabsf(a31);
    if (xnorm == 0.f) {
      tau1 = 0.f; v2 = 0.f;
      dd[0] = a11; dd[1] = a22; dd[2] = a33; ee[0] = alpha; ee[1] = a32;
    } else {
      float beta = -copysignf(lapy2f(alpha, xnorm), alpha);
      tau1 = (beta - alpha) / beta;
      v2 = a31 * (1.f / (alpha - beta));  // DSCAL: reciprocal then multiply
      float y1 = tau1 * a22; y1 = y1 + tau1 * (a32 * v2);
      float y2 = tau1 * a32; y2 = y2 + (tau1 * v2) * a33;
      float dotv = y1; dotv = dotv + y2 * v2;
      float ac = -0.5f * tau1 * dotv;
      y1 = y1 + ac;
      y2 = y2 + ac * v2;
      float t1 = -y1, t2 = -1.f;
      a22 = (a22 + t1) + y1 * t2;
      a32 = (a32 + v2 * t1) + y2 * t2;
      float t1b = -y2, t2b = -v2;
      a33 = (a33 + v2 * t1b) + y2 * t2b;
      dd[0] = a11; dd[1] = a22; dd[2] = a33; ee[0] = beta; ee[1] = a32;
    }
  }
  float z[3][3] = {{1.f, 0.f, 0.f}, {0.f, 1.f, 0.f}, {0.f, 0.f, 1.f}};
  ssteqr3(dd, ee, z);
  if (tau1 != 0.f) {
    float w = tau1 * (z[1][0] + v2 * z[2][0]);
    z[1][0] = z[1][0] - w;
    z[2][0] = z[2][0] - v2 * w;
  }
  nrm[3 * i]     = z[0][0];
  nrm[3 * i + 1] = z[1][0];
  nrm[3 * i + 2] = z[2][0];
}

// ---------------- Kernel 3: PPF features + mean + head matmul ----------------

__device__ __forceinline__ float angle3(float ax, float ay, float az,
                                        float bx, float by, float bz) {
  float cx = ay * bz - az * by;
  float cy = az * bx - ax * bz;
  float cz = ax * by - ay * bx;
  float sq = cx * cx + cy * cy + cz * cz;
  float nrmc = (sq > 0.f) ? sqrtf(sq) : 0.f;
  float dot = ax * bx + ay * by + az * bz;
  return atan2f(nrmc, dot);
}

__global__ __launch_bounds__(256) void ppf_kernel(const float* __restrict__ pts,
                                                  const float* __restrict__ nrm,
                                                  const float* __restrict__ Wm,
                                                  const float* __restrict__ bias,
                                                  float* __restrict__ out) {
  int i = blockIdx.x;
  float px = pts[3 * i], py = pts[3 * i + 1], pz = pts[3 * i + 2];
  float ax = nrm[3 * i], ay = nrm[3 * i + 1], az = nrm[3 * i + 2];
  float s0 = 0.f, s1 = 0.f, s2 = 0.f, s3 = 0.f;
  for (int j = threadIdx.x; j < NPTS; j += 256) {
    float dx = px - pts[3 * j];
    float dy = py - pts[3 * j + 1];
    float dz = pz - pts[3 * j + 2];
    float bx = nrm[3 * j], by = nrm[3 * j + 1], bz = nrm[3 * j + 2];
    float sq = dx * dx + dy * dy + dz * dz;
    s0 += (sq > 0.f) ? sqrtf(sq) : 0.f;
    s1 += angle3(ax, ay, az, dx, dy, dz);
    s2 += angle3(bx, by, bz, dx, dy, dz);
    s3 += angle3(ax, ay, az, bx, by, bz);
  }
  __shared__ float red[4][256];
  int tid = threadIdx.x;
  red[0][tid] = s0; red[1][tid] = s1; red[2][tid] = s2; red[3][tid] = s3;
  __syncthreads();
  for (int off = 128; off > 0; off >>= 1) {
    if (tid < off) {
      red[0][tid] += red[0][tid + off];
      red[1][tid] += red[1][tid + off];
      red[2][tid] += red[2][tid + off];
      red[3][tid] += red[3][tid + off];
    }
    __syncthreads();
  }
  float f0 = red[0][0] / 2048.f;
  float f1 = red[1][0] / 2048.f;
  float f2 = red[2][0] / 2048.f;
  float f3 = red[3][0] / 2048.f;
  int o = tid;  // NOUT == blockDim.x == 256
  float w0 = Wm[4 * o], w1 = Wm[4 * o + 1], w2 = Wm[4 * o + 2], w3 = Wm[4 * o + 3];
  out[i * NOUT + o] = (((f0 * w0 + f1 * w1) + f2 * w2) + f3 * w3) + bias[o];
}

// ---------------- launcher ----------------

extern "C" void kernel_launch(void* const* d_in, const int* in_sizes, int n_in,
                              void* d_out, int out_size, void* d_ws, size_t ws_size,
                              hipStream_t stream) {
  const float* pts = (const float*)d_in[0];   // (1,2048,3) fp32
  const float* Wm  = (const float*)d_in[1];   // (256,4) fp32
  const float* bs  = (const float*)d_in[2];   // (256,) fp32
  float* out = (float*)d_out;                 // (1,2048,256) fp32
  float* nrm = (float*)d_ws;                                  // 2048*3 floats
  int*   knn = (int*)((char*)d_ws + NPTS * 3 * sizeof(float)); // 2048*10 ints

  knn_select_kernel<<<NPTS, 256, 0, stream>>>(pts, knn);
  normals_kernel<<<NPTS / 256, 256, 0, stream>>>(pts, knn, nrm);
  ppf_kernel<<<NPTS, 256, 0, stream>>>(pts, nrm, Wm, bs, out);
}

// Round 3
// 121.951 us; speedup vs baseline: 5.6258x; 1.1135x over previous
//
#include <hip/hip_runtime.h>
#include <math.h>

// Default: no FMA contraction — KNN distance order and the LAPACK-faithful
// eigh path must match the reference bitwise. The tolerant PPF path opts
// back into contract(fast) locally.
#pragma clang fp contract(off)

#define NPTS 2048
#define KNN 10
#define NOUT 256

// ---------------- LAPACK-faithful fp32 helpers ----------------

__device__ __forceinline__ float lapy2f(float x, float y) {
  float xa = fabsf(x), ya = fabsf(y);
  float w = fmaxf(xa, ya), z = fminf(xa, ya);
  if (z == 0.f) return w;
  float t = z / w;
  return w * sqrtf(1.f + t * t);
}

// SLARTG, LAPACK >= 3.10 convention (modern OpenBLAS / numpy wheels).
__device__ __forceinline__ void slartgf(float f, float g, float& c, float& s, float& r) {
  if (g == 0.f) { c = 1.f; s = 0.f; r = f; }
  else if (f == 0.f) { c = 0.f; s = copysignf(1.f, g); r = fabsf(g); }
  else {
    float d = sqrtf(f * f + g * g);
    float p = 1.f / d;
    c = fabsf(f) * p;
    s = g * copysignf(p, f);
    r = copysignf(d, f);
  }
}

__device__ void slaev2f(float a, float b, float c,
                        float& rt1, float& rt2, float& cs1, float& sn1) {
  float sm = a + c;
  float df = a - c;
  float adf = fabsf(df);
  float tb = b + b;
  float ab = fabsf(tb);
  float acmx, acmn;
  if (fabsf(a) > fabsf(c)) { acmx = a; acmn = c; } else { acmx = c; acmn = a; }
  float rt;
  if (adf > ab)      { float t = ab / adf; rt = adf * sqrtf(1.f + t * t); }
  else if (adf < ab) { float t = adf / ab; rt = ab * sqrtf(1.f + t * t); }
  else               { rt = ab * sqrtf(2.f); }
  int sgn1;
  if (sm < 0.f) {
    rt1 = 0.5f * (sm - rt); sgn1 = -1;
    rt2 = (acmx / rt1) * acmn - (b / rt1) * b;
  } else if (sm > 0.f) {
    rt1 = 0.5f * (sm + rt); sgn1 = 1;
    rt2 = (acmx / rt1) * acmn - (b / rt1) * b;
  } else {
    rt1 = 0.5f * rt; rt2 = -0.5f * rt; sgn1 = 1;
  }
  int sgn2; float cs;
  if (df >= 0.f) { cs = df + rt; sgn2 = 1; } else { cs = df - rt; sgn2 = -1; }
  float acs = fabsf(cs);
  if (acs > ab) {
    float ct = -tb / cs;
    sn1 = 1.f / sqrtf(1.f + ct * ct);
    cs1 = ct * sn1;
  } else {
    if (ab == 0.f) { cs1 = 1.f; sn1 = 0.f; }
    else {
      float tn = -cs / tb;
      cs1 = 1.f / sqrtf(1.f + tn * tn);
      sn1 = tn * cs1;
    }
  }
  if (sgn1 == sgn2) { float tn = cs1; cs1 = -sn1; sn1 = tn; }
}

__device__ __forceinline__ void rot_cols(float z[3][3], int j1, int j2, float c, float s) {
  for (int i = 0; i < 3; ++i) {
    float temp = z[i][j2 - 1];
    z[i][j2 - 1] = c * temp - s * z[i][j1 - 1];
    z[i][j1 - 1] = s * temp + c * z[i][j1 - 1];
  }
}

// SSTEQR('I', n=3) faithful port. dd[3], ee[2], z init to identity.
__device__ void ssteqr3(float* dd, float* ee, float z[3][3]) {
  const float eps = 5.9604645e-8f;
  const float eps2 = eps * eps;
  const float safmin = 1.1754944e-38f;
  const int n = 3, nm1 = 2;
  const int nmaxit = 90;
  int jtot = 0;
  float wc[2], wsn[2];
  int l1 = 1;
  for (int og = 0; og < 64; ++og) {
    if (l1 > n) break;
    if (l1 > 1) ee[l1 - 2] = 0.f;
    int m = n;
    if (l1 <= nm1) {
      for (int mm = l1; mm <= nm1; ++mm) {
        float tst = fabsf(ee[mm - 1]);
        if (tst == 0.f) { m = mm; break; }
        if (tst <= (sqrtf(fabsf(dd[mm - 1])) * sqrtf(fabsf(dd[mm]))) * eps) {
          ee[mm - 1] = 0.f; m = mm; break;
        }
      }
    }
    int l = l1, lend = m;
    l1 = m + 1;
    if (lend == l) continue;
    if (fabsf(dd[lend - 1]) < fabsf(dd[l - 1])) { int t = lend; lend = l; l = t; }
    if (lend > l) {
      for (int it = 0; it < 256; ++it) {
        int m2 = lend;
        if (l != lend) {
          for (int mm = l; mm <= lend - 1; ++mm) {
            float tst = ee[mm - 1] * ee[mm - 1];
            if (tst <= (eps2 * fabsf(dd[mm - 1])) * fabsf(dd[mm]) + safmin) { m2 = mm; break; }
          }
        }
        if (m2 < lend) ee[m2 - 1] = 0.f;
        float p = dd[l - 1];
        if (m2 == l) {
          dd[l - 1] = p;
          l += 1;
          if (l <= lend) continue;
          break;
        }
        if (m2 == l + 1) {
          float rt1, rt2, c, s;
          slaev2f(dd[l - 1], ee[l - 1], dd[l], rt1, rt2, c, s);
          rot_cols(z, l, l + 1, c, s);
          dd[l - 1] = rt1; dd[l] = rt2; ee[l - 1] = 0.f;
          l += 2;
          if (l <= lend) continue;
          break;
        }
        if (jtot == nmaxit) break;
        jtot++;
        float g = (dd[l] - p) / (2.f * ee[l - 1]);
        float r = lapy2f(g, 1.f);
        g = dd[m2 - 1] - p + ee[l - 1] / (g + copysignf(r, g));
        float s = 1.f, c = 1.f;
        p = 0.f;
        for (int i = m2 - 1; i >= l; --i) {
          float f = s * ee[i - 1];
          float bb = c * ee[i - 1];
          slartgf(g, f, c, s, r);
          if (i != m2 - 1) ee[i] = r;
          g = dd[i] - p;
          r = (dd[i - 1] - g) * s + 2.f * c * bb;
          p = s * r;
          dd[i] = g + p;
          g = c * r - bb;
          wc[i - 1] = c;
          wsn[i - 1] = -s;
        }
        int mm = m2 - l + 1;
        for (int j = mm - 1; j >= 1; --j)
          rot_cols(z, l + j - 1, l + j, wc[l + j - 2], wsn[l + j - 2]);
        dd[l - 1] = dd[l - 1] - p;
        ee[l - 1] = g;
      }
    } else {
      for (int it = 0; it < 256; ++it) {
        int m2 = lend;
        if (l != lend) {
          for (int mm = l; mm >= lend + 1; --mm) {
            float tst = ee[mm - 2] * ee[mm - 2];
            if (tst <= (eps2 * fabsf(dd[mm - 1])) * fabsf(dd[mm - 2]) + safmin) { m2 = mm; break; }
          }
        }
        if (m2 > lend) ee[m2 - 2] = 0.f;
        float p = dd[l - 1];
        if (m2 == l) {
          dd[l - 1] = p;
          l -= 1;
          if (l >= lend) continue;
          break;
        }
        if (m2 == l - 1) {
          float rt1, rt2, c, s;
          slaev2f(dd[l - 2], ee[l - 2], dd[l - 1], rt1, rt2, c, s);
          rot_cols(z, l - 1, l, c, s);
          dd[l - 2] = rt1; dd[l - 1] = rt2; ee[l - 2] = 0.f;
          l -= 2;
          if (l >= lend) continue;
          break;
        }
        if (jtot == nmaxit) break;
        jtot++;
        float g = (dd[l - 2] - p) / (2.f * ee[l - 2]);
        float r = lapy2f(g, 1.f);
        g = dd[m2 - 1] - p + ee[l - 2] / (g + copysignf(r, g));
        float s = 1.f, c = 1.f;
        p = 0.f;
        for (int i = m2; i <= l - 1; ++i) {
          float f = s * ee[i - 1];
          float bb = c * ee[i - 1];
          slartgf(g, f, c, s, r);
          if (i != m2) ee[i - 2] = r;
          g = dd[i - 1] - p;
          r = (dd[i] - g) * s + 2.f * c * bb;
          p = s * r;
          dd[i - 1] = g + p;
          g = c * r - bb;
          wc[i - 1] = c;
          wsn[i - 1] = s;
        }
        int mm = l - m2 + 1;
        for (int j = 1; j <= mm - 1; ++j)
          rot_cols(z, m2 + j - 1, m2 + j, wc[m2 + j - 2], wsn[m2 + j - 2]);
        dd[l - 1] = dd[l - 1] - p;
        ee[l - 2] = g;
      }
    }
  }
  for (int ii = 2; ii <= n; ++ii) {
    int i = ii - 1, k = i;
    float p = dd[i - 1];
    for (int j = ii; j <= n; ++j) {
      if (dd[j - 1] < p) { k = j; p = dd[j - 1]; }
    }
    if (k != i) {
      dd[k - 1] = dd[i - 1]; dd[i - 1] = p;
      for (int r0 = 0; r0 < 3; ++r0) {
        float t = z[r0][i - 1]; z[r0][i - 1] = z[r0][k - 1]; z[r0][k - 1] = t;
      }
    }
  }
}

// ---------------- Kernel 1: KNN select, one WAVE per point ----------------
// 64 lanes x 32 candidates (4 sorted groups of 8). Key = (sq_bits<<32)|j:
// fp32 sq >= 0 so uint order == float order; low index bits reproduce jax
// top_k's lower-index tie-break exactly. 11 pop rounds via pure wave
// shuffles — zero __syncthreads, zero LDS.

__global__ __launch_bounds__(64) void knn_select_kernel(const float* __restrict__ pts,
                                                        int* __restrict__ knn) {
  const int i = blockIdx.x;
  const int lane = threadIdx.x;
  float px = pts[3 * i], py = pts[3 * i + 1], pz = pts[3 * i + 2];

  unsigned long long k0[8], k1[8], k2[8], k3[8];
#define DIST(g, arr)                                                      \
  {                                                                       \
    _Pragma("unroll")                                                     \
    for (int t = 0; t < 8; ++t) {                                         \
      int j = ((g) * 8 + t) * 64 + lane;                                  \
      float dx = px - pts[3 * j];                                         \
      float dy = py - pts[3 * j + 1];                                     \
      float dz = pz - pts[3 * j + 2];                                     \
      float sq = dx * dx;                                                 \
      sq = sq + dy * dy;                                                  \
      sq = sq + dz * dz;                                                  \
      arr[t] = (((unsigned long long)__float_as_uint(sq)) << 32) |        \
               (unsigned int)j;                                           \
    }                                                                     \
  }
  DIST(0, k0) DIST(1, k1) DIST(2, k2) DIST(3, k3)
#undef DIST

  // branch-free sort of 8 keys: 19-comparator optimal network (same as R2)
#define CE(arr, a, b)                                                     \
  {                                                                       \
    unsigned long long lo = arr[a] < arr[b] ? arr[a] : arr[b];            \
    unsigned long long hi = arr[a] < arr[b] ? arr[b] : arr[a];            \
    arr[a] = lo; arr[b] = hi;                                             \
  }
#define SORT8(arr)                                                        \
  CE(arr, 0, 1) CE(arr, 2, 3) CE(arr, 4, 5) CE(arr, 6, 7)                 \
  CE(arr, 0, 2) CE(arr, 1, 3) CE(arr, 4, 6) CE(arr, 5, 7)                 \
  CE(arr, 1, 2) CE(arr, 5, 6) CE(arr, 0, 4) CE(arr, 3, 7)                 \
  CE(arr, 1, 5) CE(arr, 2, 6)                                             \
  CE(arr, 1, 4) CE(arr, 3, 6)                                             \
  CE(arr, 2, 4) CE(arr, 3, 5)                                             \
  CE(arr, 3, 4)
  SORT8(k0) SORT8(k1) SORT8(k2) SORT8(k3)
#undef SORT8
#undef CE

#define POP(arr)                                                          \
  {                                                                       \
    _Pragma("unroll")                                                     \
    for (int q = 0; q < 7; ++q) arr[q] = arr[q + 1];                      \
    arr[7] = 0xFFFFFFFFFFFFFFFFULL;                                       \
  }

  // 11 rounds: round 0 pops self (sq=0); rounds 1..10 emit neighbors in
  // exact top_k order. A group supplies at most 8 then reads as MAX.
  for (int r = 0; r < KNN + 1; ++r) {
    unsigned long long h01 = k0[0] < k1[0] ? k0[0] : k1[0];
    unsigned long long h23 = k2[0] < k3[0] ? k2[0] : k3[0];
    unsigned long long h = h01 < h23 ? h01 : h23;
    unsigned long long m = h;
#pragma unroll
    for (int off = 32; off > 0; off >>= 1) {
      unsigned long long o = __shfl_xor(m, off, 64);
      m = (o < m) ? o : m;
    }
    if (r > 0 && lane == 0) knn[i * KNN + (r - 1)] = (int)(unsigned int)m;
    if (h == m) {  // unique winner (index bits make keys distinct)
      if (k0[0] == m)      { POP(k0) }
      else if (k1[0] == m) { POP(k1) }
      else if (k2[0] == m) { POP(k2) }
      else                 { POP(k3) }
    }
  }
#undef POP
}

// ---------------- Kernel 2: covariance + eigh -> normals (one thread per point) ----------------

__global__ __launch_bounds__(256) void normals_kernel(const float* __restrict__ pts,
                                                      const int* __restrict__ knn,
                                                      float* __restrict__ nrm) {
  int i = blockIdx.x * 256 + threadIdx.x;
  if (i >= NPTS) return;

  float nx[KNN], ny[KNN], nz[KNN];
  float sx = 0.f, sy = 0.f, sz = 0.f;
  for (int t = 0; t < KNN; ++t) {
    int j = knn[i * KNN + t];
    nx[t] = pts[3 * j]; ny[t] = pts[3 * j + 1]; nz[t] = pts[3 * j + 2];
    sx = sx + nx[t]; sy = sy + ny[t]; sz = sz + nz[t];
  }
  float mx = sx / 10.f, my = sy / 10.f, mz = sz / 10.f;
  float a11 = 0.f, a21 = 0.f, a31 = 0.f, a22 = 0.f, a32 = 0.f, a33 = 0.f;
  for (int t = 0; t < KNN; ++t) {
    float cx = nx[t] - mx, cy = ny[t] - my, cz = nz[t] - mz;
    a11 = a11 + cx * cx;
    a21 = a21 + cy * cx;
    a31 = a31 + cz * cx;
    a22 = a22 + cy * cy;
    a32 = a32 + cz * cy;
    a33 = a33 + cz * cz;
  }
  a11 = a11 / 10.f; a21 = a21 / 10.f; a31 = a31 / 10.f;
  a22 = a22 / 10.f; a32 = a32 / 10.f; a33 = a33 / 10.f;

  // SSYTD2 (uplo='L', n=3): one Householder reflector
  float dd[3], ee[2], tau1 = 0.f, v2 = 0.f;
  {
    float alpha = a21;
    float xnorm = fabsf(a31);
    if (xnorm == 0.f) {
      tau1 = 0.f; v2 = 0.f;
      dd[0] = a11; dd[1] = a22; dd[2] = a33; ee[0] = alpha; ee[1] = a32;
    } else {
      float beta = -copysignf(lapy2f(alpha, xnorm), alpha);
      tau1 = (beta - alpha) / beta;
      v2 = a31 * (1.f / (alpha - beta));  // DSCAL: reciprocal then multiply
      float y1 = tau1 * a22; y1 = y1 + tau1 * (a32 * v2);
      float y2 = tau1 * a32; y2 = y2 + (tau1 * v2) * a33;
      float dotv = y1; dotv = dotv + y2 * v2;
      float ac = -0.5f * tau1 * dotv;
      y1 = y1 + ac;
      y2 = y2 + ac * v2;
      float t1 = -y1, t2 = -1.f;
      a22 = (a22 + t1) + y1 * t2;
      a32 = (a32 + v2 * t1) + y2 * t2;
      float t1b = -y2, t2b = -v2;
      a33 = (a33 + v2 * t1b) + y2 * t2b;
      dd[0] = a11; dd[1] = a22; dd[2] = a33; ee[0] = beta; ee[1] = a32;
    }
  }
  float z[3][3] = {{1.f, 0.f, 0.f}, {0.f, 1.f, 0.f}, {0.f, 0.f, 1.f}};
  ssteqr3(dd, ee, z);
  if (tau1 != 0.f) {
    float w = tau1 * (z[1][0] + v2 * z[2][0]);
    z[1][0] = z[1][0] - w;
    z[2][0] = z[2][0] - v2 * w;
  }
  nrm[3 * i]     = z[0][0];
  nrm[3 * i + 1] = z[1][0];
  nrm[3 * i + 2] = z[2][0];
}

// ---------------- Kernel 3: PPF features + mean + head matmul ----------------
// Tolerant path: contract(fast) + polynomial atan2 (A&S 4.4.49, |err|<=1e-5
// rad). Output threshold 3.48e-2; R2 absmax was 7.8e-3 — ample slack.

__device__ __forceinline__ float atan2_pos(float y, float x) {
#pragma clang fp contract(fast)
  // y >= 0; returns atan2(y, x) in [0, pi]
  float axx = fabsf(x);
  float mn = fminf(axx, y), mx = fmaxf(axx, y);
  float a = mn * __builtin_amdgcn_rcpf(mx);
  a = (mx == 0.f) ? 0.f : a;  // atan2(0,0) = 0; also kills 0*inf NaN
  float s = a * a;
  float r = a * (0.9998660f +
           s * (-0.3302995f +
           s * (0.1801410f +
           s * (-0.0851330f +
           s * 0.0208351f))));
  r = (y > axx) ? 1.57079632679f - r : r;
  r = (x < 0.f) ? 3.14159265359f - r : r;
  return r;
}

__device__ __forceinline__ float angle3(float ax, float ay, float az,
                                        float bx, float by, float bz) {
#pragma clang fp contract(fast)
  float cx = ay * bz - az * by;
  float cy = az * bx - ax * bz;
  float cz = ax * by - ay * bx;
  float sq = cx * cx + cy * cy + cz * cz;
  float dot = ax * bx + ay * by + az * bz;
  return atan2_pos(sqrtf(sq), dot);
}

__global__ __launch_bounds__(256) void ppf_kernel(const float* __restrict__ pts,
                                                  const float* __restrict__ nrm,
                                                  const float* __restrict__ Wm,
                                                  const float* __restrict__ bias,
                                                  float* __restrict__ out) {
#pragma clang fp contract(fast)
  int i = blockIdx.x;
  float px = pts[3 * i], py = pts[3 * i + 1], pz = pts[3 * i + 2];
  float ax = nrm[3 * i], ay = nrm[3 * i + 1], az = nrm[3 * i + 2];
  float s0 = 0.f, s1 = 0.f, s2 = 0.f, s3 = 0.f;
  for (int j = threadIdx.x; j < NPTS; j += 256) {
    float dx = px - pts[3 * j];
    float dy = py - pts[3 * j + 1];
    float dz = pz - pts[3 * j + 2];
    float bx = nrm[3 * j], by = nrm[3 * j + 1], bz = nrm[3 * j + 2];
    float sq = dx * dx + dy * dy + dz * dz;
    s0 += sqrtf(sq);
    s1 += angle3(ax, ay, az, dx, dy, dz);
    s2 += angle3(bx, by, bz, dx, dy, dz);
    s3 += angle3(ax, ay, az, bx, by, bz);
  }
  __shared__ float red[4][256];
  int tid = threadIdx.x;
  red[0][tid] = s0; red[1][tid] = s1; red[2][tid] = s2; red[3][tid] = s3;
  __syncthreads();
  for (int off = 128; off > 0; off >>= 1) {
    if (tid < off) {
      red[0][tid] += red[0][tid + off];
      red[1][tid] += red[1][tid + off];
      red[2][tid] += red[2][tid + off];
      red[3][tid] += red[3][tid + off];
    }
    __syncthreads();
  }
  float f0 = red[0][0] / 2048.f;
  float f1 = red[1][0] / 2048.f;
  float f2 = red[2][0] / 2048.f;
  float f3 = red[3][0] / 2048.f;
  int o = tid;  // NOUT == blockDim.x == 256
  float w0 = Wm[4 * o], w1 = Wm[4 * o + 1], w2 = Wm[4 * o + 2], w3 = Wm[4 * o + 3];
  out[i * NOUT + o] = (((f0 * w0 + f1 * w1) + f2 * w2) + f3 * w3) + bias[o];
}

// ---------------- launcher ----------------

extern "C" void kernel_launch(void* const* d_in, const int* in_sizes, int n_in,
                              void* d_out, int out_size, void* d_ws, size_t ws_size,
                              hipStream_t stream) {
  const float* pts = (const float*)d_in[0];   // (1,2048,3) fp32
  const float* Wm  = (const float*)d_in[1];   // (256,4) fp32
  const float* bs  = (const float*)d_in[2];   // (256,) fp32
  float* out = (float*)d_out;                 // (1,2048,256) fp32
  float* nrm = (float*)d_ws;                                   // 2048*3 floats
  int*   knn = (int*)((char*)d_ws + NPTS * 3 * sizeof(float)); // 2048*10 ints

  knn_select_kernel<<<NPTS, 64, 0, stream>>>(pts, knn);
  normals_kernel<<<NPTS / 256, 256, 0, stream>>>(pts, knn, nrm);
  ppf_kernel<<<NPTS, 256, 0, stream>>>(pts, nrm, Wm, bs, out);
}

// Round 4
// 109.101 us; speedup vs baseline: 6.2885x; 1.1178x over previous
//
#include <hip/hip_runtime.h>
#include <math.h>

// Default: no FMA contraction — KNN distance order and the LAPACK-faithful
// eigh path must match the reference bitwise. The tolerant PPF path opts
// back into contract(fast) locally.
#pragma clang fp contract(off)

#define NPTS 2048
#define KNN 10
#define NOUT 256

// ---------------- LAPACK-faithful fp32 helpers ----------------

__device__ __forceinline__ float lapy2f(float x, float y) {
  float xa = fabsf(x), ya = fabsf(y);
  float w = fmaxf(xa, ya), z = fminf(xa, ya);
  if (z == 0.f) return w;
  float t = z / w;
  return w * sqrtf(1.f + t * t);
}

// SLARTG, LAPACK >= 3.10 convention (modern OpenBLAS / numpy wheels).
__device__ __forceinline__ void slartgf(float f, float g, float& c, float& s, float& r) {
  if (g == 0.f) { c = 1.f; s = 0.f; r = f; }
  else if (f == 0.f) { c = 0.f; s = copysignf(1.f, g); r = fabsf(g); }
  else {
    float d = sqrtf(f * f + g * g);
    float p = 1.f / d;
    c = fabsf(f) * p;
    s = g * copysignf(p, f);
    r = copysignf(d, f);
  }
}

__device__ __forceinline__ void slaev2f(float a, float b, float c,
                                        float& rt1, float& rt2, float& cs1, float& sn1) {
  float sm = a + c;
  float df = a - c;
  float adf = fabsf(df);
  float tb = b + b;
  float ab = fabsf(tb);
  float acmx, acmn;
  if (fabsf(a) > fabsf(c)) { acmx = a; acmn = c; } else { acmx = c; acmn = a; }
  float rt;
  if (adf > ab)      { float t = ab / adf; rt = adf * sqrtf(1.f + t * t); }
  else if (adf < ab) { float t = adf / ab; rt = ab * sqrtf(1.f + t * t); }
  else               { rt = ab * sqrtf(2.f); }
  int sgn1;
  if (sm < 0.f) {
    rt1 = 0.5f * (sm - rt); sgn1 = -1;
    rt2 = (acmx / rt1) * acmn - (b / rt1) * b;
  } else if (sm > 0.f) {
    rt1 = 0.5f * (sm + rt); sgn1 = 1;
    rt2 = (acmx / rt1) * acmn - (b / rt1) * b;
  } else {
    rt1 = 0.5f * rt; rt2 = -0.5f * rt; sgn1 = 1;
  }
  int sgn2; float cs;
  if (df >= 0.f) { cs = df + rt; sgn2 = 1; } else { cs = df - rt; sgn2 = -1; }
  float acs = fabsf(cs);
  if (acs > ab) {
    float ct = -tb / cs;
    sn1 = 1.f / sqrtf(1.f + ct * ct);
    cs1 = ct * sn1;
  } else {
    if (ab == 0.f) { cs1 = 1.f; sn1 = 0.f; }
    else {
      float tn = -cs / tb;
      cs1 = 1.f / sqrtf(1.f + tn * tn);
      sn1 = tn * cs1;
    }
  }
  if (sgn1 == sgn2) { float tn = cs1; cs1 = -sn1; sn1 = tn; }
}

// Column rotations on the scalarized 3x3 eigenvector matrix (z[row][col]).
// Exact op order of the reference's rot_cols (DLASR body).
#define ROT12(c, s) {                                         \
    float t_;                                                 \
    t_ = z01; z01 = (c) * t_ - (s) * z00; z00 = (s) * t_ + (c) * z00; \
    t_ = z11; z11 = (c) * t_ - (s) * z10; z10 = (s) * t_ + (c) * z10; \
    t_ = z21; z21 = (c) * t_ - (s) * z20; z20 = (s) * t_ + (c) * z20; }
#define ROT23(c, s) {                                         \
    float t_;                                                 \
    t_ = z02; z02 = (c) * t_ - (s) * z01; z01 = (s) * t_ + (c) * z01; \
    t_ = z12; z12 = (c) * t_ - (s) * z11; z11 = (s) * t_ + (c) * z11; \
    t_ = z22; z22 = (c) * t_ - (s) * z21; z21 = (s) * t_ + (c) * z21; }

// SSTEQR('I', n=3), fully scalarized: all state in VGPRs, zero scratch.
// Runtime-index specialization facts (n=3): the full implicit-shift QL step
// only fires at (l,m2,lend)=(1,3,3); the full QR step only at (3,1,1) — the
// m2==l and m2==l±1 cases are peeled first. Arithmetic op order is identical
// to the reference array version.
__device__ __forceinline__ void ssteqr3_reg(
    float& d0, float& d1, float& d2, float& e0, float& e1,
    float& z00, float& z01, float& z02,
    float& z10, float& z11, float& z12,
    float& z20, float& z21, float& z22) {
  const float eps = 5.9604645e-8f;
  const float eps2 = eps * eps;
  const float safmin = 1.1754944e-38f;
  const int nmaxit = 90;
  int jtot = 0;
  int l1 = 1;
  for (int og = 0; og < 4; ++og) {   // l1 strictly increases -> <=3 iters
    if (l1 > 3) break;
    if (l1 == 2) e0 = 0.f;
    else if (l1 == 3) e1 = 0.f;
    int m = 3;
    if (l1 == 1) {
      float t = fabsf(e0);
      if (t == 0.f) m = 1;
      else if (t <= (sqrtf(fabsf(d0)) * sqrtf(fabsf(d1))) * eps) { e0 = 0.f; m = 1; }
      else {
        float t2 = fabsf(e1);
        if (t2 == 0.f) m = 2;
        else if (t2 <= (sqrtf(fabsf(d1)) * sqrtf(fabsf(d2))) * eps) { e1 = 0.f; m = 2; }
      }
    } else if (l1 == 2) {
      float t = fabsf(e1);
      if (t == 0.f) m = 2;
      else if (t <= (sqrtf(fabsf(d1)) * sqrtf(fabsf(d2))) * eps) { e1 = 0.f; m = 2; }
    }
    int l = l1, lend = m;
    l1 = m + 1;
    if (lend == l) continue;
    {
      float dlend = (lend == 1) ? d0 : ((lend == 2) ? d1 : d2);
      float dl = (l == 1) ? d0 : ((l == 2) ? d1 : d2);
      if (fabsf(dlend) < fabsf(dl)) { int t = lend; lend = l; l = t; }
    }
    if (lend > l) {
      // ---- QL iteration ----
      for (int it = 0; it < 128; ++it) {
        int m2 = lend;
        if (l != lend) {
          for (int mm = l; mm <= lend - 1; ++mm) {  // mm in {1,2}
            float em  = (mm == 1) ? e0 : e1;
            float dm1 = (mm == 1) ? d0 : d1;
            float dm  = (mm == 1) ? d1 : d2;
            float tst = em * em;
            if (tst <= (eps2 * fabsf(dm1)) * fabsf(dm) + safmin) { m2 = mm; break; }
          }
        }
        if (m2 < lend) { if (m2 == 1) e0 = 0.f; else e1 = 0.f; }
        float p = (l == 1) ? d0 : ((l == 2) ? d1 : d2);
        if (m2 == l) { l += 1; if (l <= lend) continue; break; }
        if (m2 == l + 1) {
          float rt1, rt2, c, s;
          if (l == 1) {
            slaev2f(d0, e0, d1, rt1, rt2, c, s);
            ROT12(c, s)
            d0 = rt1; d1 = rt2; e0 = 0.f;
          } else {  // l == 2
            slaev2f(d1, e1, d2, rt1, rt2, c, s);
            ROT23(c, s)
            d1 = rt1; d2 = rt2; e1 = 0.f;
          }
          l += 2; if (l <= lend) continue; break;
        }
        if (jtot == nmaxit) break;
        jtot++;
        // full QL step: l=1, m2=3, lend=3 (fixed indices)
        float g = (d1 - p) / (2.f * e0);
        float r = lapy2f(g, 1.f);
        g = d2 - p + e0 / (g + copysignf(r, g));
        float s = 1.f, c = 1.f;
        p = 0.f;
        float c0, s0n, c1, s1n;
        {  // i = 2
          float f = s * e1;
          float bb = c * e1;
          slartgf(g, f, c, s, r);
          g = d2 - p;
          r = (d1 - g) * s + 2.f * c * bb;
          p = s * r;
          d2 = g + p;
          g = c * r - bb;
          c1 = c; s1n = -s;
        }
        {  // i = 1
          float f = s * e0;
          float bb = c * e0;
          slartgf(g, f, c, s, r);
          e1 = r;
          g = d1 - p;
          r = (d0 - g) * s + 2.f * c * bb;
          p = s * r;
          d1 = g + p;
          g = c * r - bb;
          c0 = c; s0n = -s;
        }
        ROT23(c1, s1n)
        ROT12(c0, s0n)
        d0 = d0 - p;
        e0 = g;
      }
    } else {
      // ---- QR iteration ----
      for (int it = 0; it < 128; ++it) {
        int m2 = lend;
        if (l != lend) {
          for (int mm = l; mm >= lend + 1; --mm) {  // mm in {3,2}
            float em  = (mm == 3) ? e1 : e0;
            float dm1 = (mm == 3) ? d2 : d1;
            float dm2 = (mm == 3) ? d1 : d0;
            float tst = em * em;
            if (tst <= (eps2 * fabsf(dm1)) * fabsf(dm2) + safmin) { m2 = mm; break; }
          }
        }
        if (m2 > lend) { if (m2 == 3) e1 = 0.f; else e0 = 0.f; }
        float p = (l == 1) ? d0 : ((l == 2) ? d1 : d2);
        if (m2 == l) { l -= 1; if (l >= lend) continue; break; }
        if (m2 == l - 1) {
          float rt1, rt2, c, s;
          if (l == 2) {
            slaev2f(d0, e0, d1, rt1, rt2, c, s);
            ROT12(c, s)
            d0 = rt1; d1 = rt2; e0 = 0.f;
          } else {  // l == 3
            slaev2f(d1, e1, d2, rt1, rt2, c, s);
            ROT23(c, s)
            d1 = rt1; d2 = rt2; e1 = 0.f;
          }
          l -= 2; if (l >= lend) continue; break;
        }
        if (jtot == nmaxit) break;
        jtot++;
        // full QR step: l=3, m2=1, lend=1 (fixed indices)
        float g = (d1 - p) / (2.f * e1);
        float r = lapy2f(g, 1.f);
        g = d0 - p + e1 / (g + copysignf(r, g));
        float s = 1.f, c = 1.f;
        p = 0.f;
        float c0, s0p, c1, s1p;
        {  // i = 1
          float f = s * e0;
          float bb = c * e0;
          slartgf(g, f, c, s, r);
          g = d0 - p;
          r = (d1 - g) * s + 2.f * c * bb;
          p = s * r;
          d0 = g + p;
          g = c * r - bb;
          c0 = c; s0p = s;
        }
        {  // i = 2
          float f = s * e1;
          float bb = c * e1;
          slartgf(g, f, c, s, r);
          e0 = r;
          g = d1 - p;
          r = (d2 - g) * s + 2.f * c * bb;
          p = s * r;
          d1 = g + p;
          g = c * r - bb;
          c1 = c; s1p = s;
        }
        ROT12(c0, s0p)
        ROT23(c1, s1p)
        d2 = d2 - p;
        e1 = g;
      }
    }
  }
  // ascending eigenvalue selection sort with column swaps (DSTEQR label 160)
  {
    // ii=2 (i=1)
    int k = 1; float p = d0;
    if (d1 < p) { k = 2; p = d1; }
    if (d2 < p) { k = 3; p = d2; }
    if (k == 2) {
      d1 = d0; d0 = p;
      float t;
      t = z00; z00 = z01; z01 = t;
      t = z10; z10 = z11; z11 = t;
      t = z20; z20 = z21; z21 = t;
    } else if (k == 3) {
      d2 = d0; d0 = p;
      float t;
      t = z00; z00 = z02; z02 = t;
      t = z10; z10 = z12; z12 = t;
      t = z20; z20 = z22; z22 = t;
    }
    // ii=3 (i=2)
    k = 2; p = d1;
    if (d2 < p) { k = 3; p = d2; }
    if (k == 3) {
      d2 = d1; d1 = p;
      float t;
      t = z01; z01 = z02; z02 = t;
      t = z11; z11 = z12; z12 = t;
      t = z21; z21 = z22; z22 = t;
    }
  }
}

// ---------------- Kernel 1: KNN select, one WAVE per point ----------------
// 64 lanes x 32 candidates (4 sorted groups of 8). Key = (sq_bits<<32)|j:
// fp32 sq >= 0 so uint order == float order; low index bits reproduce jax
// top_k's lower-index tie-break exactly. 11 pop rounds via pure wave
// shuffles — zero __syncthreads, zero LDS.

__global__ __launch_bounds__(64) void knn_select_kernel(const float* __restrict__ pts,
                                                        int* __restrict__ knn) {
  const int i = blockIdx.x;
  const int lane = threadIdx.x;
  float px = pts[3 * i], py = pts[3 * i + 1], pz = pts[3 * i + 2];

  unsigned long long k0[8], k1[8], k2[8], k3[8];
#define DIST(g, arr)                                                      \
  {                                                                       \
    _Pragma("unroll")                                                     \
    for (int t = 0; t < 8; ++t) {                                         \
      int j = ((g) * 8 + t) * 64 + lane;                                  \
      float dx = px - pts[3 * j];                                         \
      float dy = py - pts[3 * j + 1];                                     \
      float dz = pz - pts[3 * j + 2];                                     \
      float sq = dx * dx;                                                 \
      sq = sq + dy * dy;                                                  \
      sq = sq + dz * dz;                                                  \
      arr[t] = (((unsigned long long)__float_as_uint(sq)) << 32) |        \
               (unsigned int)j;                                           \
    }                                                                     \
  }
  DIST(0, k0) DIST(1, k1) DIST(2, k2) DIST(3, k3)
#undef DIST

#define CE(arr, a, b)                                                     \
  {                                                                       \
    unsigned long long lo = arr[a] < arr[b] ? arr[a] : arr[b];            \
    unsigned long long hi = arr[a] < arr[b] ? arr[b] : arr[a];            \
    arr[a] = lo; arr[b] = hi;                                             \
  }
#define SORT8(arr)                                                        \
  CE(arr, 0, 1) CE(arr, 2, 3) CE(arr, 4, 5) CE(arr, 6, 7)                 \
  CE(arr, 0, 2) CE(arr, 1, 3) CE(arr, 4, 6) CE(arr, 5, 7)                 \
  CE(arr, 1, 2) CE(arr, 5, 6) CE(arr, 0, 4) CE(arr, 3, 7)                 \
  CE(arr, 1, 5) CE(arr, 2, 6)                                             \
  CE(arr, 1, 4) CE(arr, 3, 6)                                             \
  CE(arr, 2, 4) CE(arr, 3, 5)                                             \
  CE(arr, 3, 4)
  SORT8(k0) SORT8(k1) SORT8(k2) SORT8(k3)
#undef SORT8
#undef CE

#define POP(arr)                                                          \
  {                                                                       \
    _Pragma("unroll")                                                     \
    for (int q = 0; q < 7; ++q) arr[q] = arr[q + 1];                      \
    arr[7] = 0xFFFFFFFFFFFFFFFFULL;                                       \
  }

  for (int r = 0; r < KNN + 1; ++r) {
    unsigned long long h01 = k0[0] < k1[0] ? k0[0] : k1[0];
    unsigned long long h23 = k2[0] < k3[0] ? k2[0] : k3[0];
    unsigned long long h = h01 < h23 ? h01 : h23;
    unsigned long long m = h;
#pragma unroll
    for (int off = 32; off > 0; off >>= 1) {
      unsigned long long o = __shfl_xor(m, off, 64);
      m = (o < m) ? o : m;
    }
    if (r > 0 && lane == 0) knn[i * KNN + (r - 1)] = (int)(unsigned int)m;
    if (h == m) {  // unique winner (index bits make keys distinct)
      if (k0[0] == m)      { POP(k0) }
      else if (k1[0] == m) { POP(k1) }
      else if (k2[0] == m) { POP(k2) }
      else                 { POP(k3) }
    }
  }
#undef POP
}

// ---------------- Kernel 2: covariance + eigh -> normals ----------------
// One thread per point, 64-thread blocks over 32 CUs. All eigh state in
// VGPRs (scalarized ssteqr3) — zero scratch.

__global__ __launch_bounds__(64) void normals_kernel(const float* __restrict__ pts,
                                                     const int* __restrict__ knn,
                                                     float* __restrict__ nrm) {
  int i = blockIdx.x * 64 + threadIdx.x;

  float nx[KNN], ny[KNN], nz[KNN];
  float sx = 0.f, sy = 0.f, sz = 0.f;
#pragma unroll
  for (int t = 0; t < KNN; ++t) {
    int j = knn[i * KNN + t];
    nx[t] = pts[3 * j]; ny[t] = pts[3 * j + 1]; nz[t] = pts[3 * j + 2];
    sx = sx + nx[t]; sy = sy + ny[t]; sz = sz + nz[t];
  }
  float mx = sx / 10.f, my = sy / 10.f, mz = sz / 10.f;
  float a11 = 0.f, a21 = 0.f, a31 = 0.f, a22 = 0.f, a32 = 0.f, a33 = 0.f;
#pragma unroll
  for (int t = 0; t < KNN; ++t) {
    float cx = nx[t] - mx, cy = ny[t] - my, cz = nz[t] - mz;
    a11 = a11 + cx * cx;
    a21 = a21 + cy * cx;
    a31 = a31 + cz * cx;
    a22 = a22 + cy * cy;
    a32 = a32 + cz * cy;
    a33 = a33 + cz * cz;
  }
  a11 = a11 / 10.f; a21 = a21 / 10.f; a31 = a31 / 10.f;
  a22 = a22 / 10.f; a32 = a32 / 10.f; a33 = a33 / 10.f;

  // SSYTD2 (uplo='L', n=3): one Householder reflector (all scalar)
  float d0, d1, d2, e0, e1, tau1 = 0.f, v2 = 0.f;
  {
    float alpha = a21;
    float xnorm = fabsf(a31);
    if (xnorm == 0.f) {
      tau1 = 0.f; v2 = 0.f;
      d0 = a11; d1 = a22; d2 = a33; e0 = alpha; e1 = a32;
    } else {
      float beta = -copysignf(lapy2f(alpha, xnorm), alpha);
      tau1 = (beta - alpha) / beta;
      v2 = a31 * (1.f / (alpha - beta));  // DSCAL: reciprocal then multiply
      float y1 = tau1 * a22; y1 = y1 + tau1 * (a32 * v2);
      float y2 = tau1 * a32; y2 = y2 + (tau1 * v2) * a33;
      float dotv = y1; dotv = dotv + y2 * v2;
      float ac = -0.5f * tau1 * dotv;
      y1 = y1 + ac;
      y2 = y2 + ac * v2;
      float t1 = -y1, t2 = -1.f;
      a22 = (a22 + t1) + y1 * t2;
      a32 = (a32 + v2 * t1) + y2 * t2;
      float t1b = -y2, t2b = -v2;
      a33 = (a33 + v2 * t1b) + y2 * t2b;
      d0 = a11; d1 = a22; d2 = a33; e0 = beta; e1 = a32;
    }
  }
  float z00 = 1.f, z01 = 0.f, z02 = 0.f;
  float z10 = 0.f, z11 = 1.f, z12 = 0.f;
  float z20 = 0.f, z21 = 0.f, z22 = 1.f;
  ssteqr3_reg(d0, d1, d2, e0, e1,
              z00, z01, z02, z10, z11, z12, z20, z21, z22);
  // DORMTR: apply H1 = I - tau*v*v^T to rows 2..3 of eigvec column 0
  if (tau1 != 0.f) {
    float w = tau1 * (z10 + v2 * z20);
    z10 = z10 - w;
    z20 = z20 - v2 * w;
  }
  nrm[3 * i]     = z00;
  nrm[3 * i + 1] = z10;
  nrm[3 * i + 2] = z20;
}

// ---------------- Kernel 3: PPF features + mean + head matmul ----------------
// Tolerant path: contract(fast) + polynomial atan2 (A&S 4.4.49, |err|<=1e-5
// rad). Output threshold 3.48e-2; R3 absmax was 1.95e-3 — ample slack.

__device__ __forceinline__ float atan2_pos(float y, float x) {
#pragma clang fp contract(fast)
  // y >= 0; returns atan2(y, x) in [0, pi]
  float axx = fabsf(x);
  float mn = fminf(axx, y), mx = fmaxf(axx, y);
  float a = mn * __builtin_amdgcn_rcpf(mx);
  a = (mx == 0.f) ? 0.f : a;  // atan2(0,0) = 0; also kills 0*inf NaN
  float s = a * a;
  float r = a * (0.9998660f +
           s * (-0.3302995f +
           s * (0.1801410f +
           s * (-0.0851330f +
           s * 0.0208351f))));
  r = (y > axx) ? 1.57079632679f - r : r;
  r = (x < 0.f) ? 3.14159265359f - r : r;
  return r;
}

__device__ __forceinline__ float angle3(float ax, float ay, float az,
                                        float bx, float by, float bz) {
#pragma clang fp contract(fast)
  float cx = ay * bz - az * by;
  float cy = az * bx - ax * bz;
  float cz = ax * by - ay * bx;
  float sq = cx * cx + cy * cy + cz * cz;
  float dot = ax * bx + ay * by + az * bz;
  return atan2_pos(sqrtf(sq), dot);
}

__global__ __launch_bounds__(256) void ppf_kernel(const float* __restrict__ pts,
                                                  const float* __restrict__ nrm,
                                                  const float* __restrict__ Wm,
                                                  const float* __restrict__ bias,
                                                  float* __restrict__ out) {
#pragma clang fp contract(fast)
  int i = blockIdx.x;
  float px = pts[3 * i], py = pts[3 * i + 1], pz = pts[3 * i + 2];
  float ax = nrm[3 * i], ay = nrm[3 * i + 1], az = nrm[3 * i + 2];
  float s0 = 0.f, s1 = 0.f, s2 = 0.f, s3 = 0.f;
  for (int j = threadIdx.x; j < NPTS; j += 256) {
    float dx = px - pts[3 * j];
    float dy = py - pts[3 * j + 1];
    float dz = pz - pts[3 * j + 2];
    float bx = nrm[3 * j], by = nrm[3 * j + 1], bz = nrm[3 * j + 2];
    float sq = dx * dx + dy * dy + dz * dz;
    s0 += sqrtf(sq);
    s1 += angle3(ax, ay, az, dx, dy, dz);
    s2 += angle3(bx, by, bz, dx, dy, dz);
    s3 += angle3(ax, ay, az, bx, by, bz);
  }
  __shared__ float red[4][256];
  int tid = threadIdx.x;
  red[0][tid] = s0; red[1][tid] = s1; red[2][tid] = s2; red[3][tid] = s3;
  __syncthreads();
  for (int off = 128; off > 0; off >>= 1) {
    if (tid < off) {
      red[0][tid] += red[0][tid + off];
      red[1][tid] += red[1][tid + off];
      red[2][tid] += red[2][tid + off];
      red[3][tid] += red[3][tid + off];
    }
    __syncthreads();
  }
  float f0 = red[0][0] / 2048.f;
  float f1 = red[1][0] / 2048.f;
  float f2 = red[2][0] / 2048.f;
  float f3 = red[3][0] / 2048.f;
  int o = tid;  // NOUT == blockDim.x == 256
  float w0 = Wm[4 * o], w1 = Wm[4 * o + 1], w2 = Wm[4 * o + 2], w3 = Wm[4 * o + 3];
  out[i * NOUT + o] = (((f0 * w0 + f1 * w1) + f2 * w2) + f3 * w3) + bias[o];
}

// ---------------- launcher ----------------

extern "C" void kernel_launch(void* const* d_in, const int* in_sizes, int n_in,
                              void* d_out, int out_size, void* d_ws, size_t ws_size,
                              hipStream_t stream) {
  const float* pts = (const float*)d_in[0];   // (1,2048,3) fp32
  const float* Wm  = (const float*)d_in[1];   // (256,4) fp32
  const float* bs  = (const float*)d_in[2];   // (256,) fp32
  float* out = (float*)d_out;                 // (1,2048,256) fp32
  float* nrm = (float*)d_ws;                                   // 2048*3 floats
  int*   knn = (int*)((char*)d_ws + NPTS * 3 * sizeof(float)); // 2048*10 ints

  knn_select_kernel<<<NPTS, 64, 0, stream>>>(pts, knn);
  normals_kernel<<<NPTS / 64, 64, 0, stream>>>(pts, knn, nrm);
  ppf_kernel<<<NPTS, 256, 0, stream>>>(pts, nrm, Wm, bs, out);
}

// Round 8
// 108.396 us; speedup vs baseline: 6.3294x; 1.0065x over previous
//
#include <hip/hip_runtime.h>
#include <math.h>

// Default: no FMA contraction — KNN distance order and the LAPACK-faithful
// eigh path must match the reference bitwise. The tolerant PPF path opts
// back into contract(fast) locally.
#pragma clang fp contract(off)

#define NPTS 2048
#define KNN 10
#define NOUT 256

// ---------------- LAPACK-faithful fp32 helpers ----------------

__device__ __forceinline__ float lapy2f(float x, float y) {
  float xa = fabsf(x), ya = fabsf(y);
  float w = fmaxf(xa, ya), z = fminf(xa, ya);
  if (z == 0.f) return w;
  float t = z / w;
  return w * sqrtf(1.f + t * t);
}

// SLARTG, LAPACK >= 3.10 convention (modern OpenBLAS / numpy wheels).
__device__ __forceinline__ void slartgf(float f, float g, float& c, float& s, float& r) {
  if (g == 0.f) { c = 1.f; s = 0.f; r = f; }
  else if (f == 0.f) { c = 0.f; s = copysignf(1.f, g); r = fabsf(g); }
  else {
    float d = sqrtf(f * f + g * g);
    float p = 1.f / d;
    c = fabsf(f) * p;
    s = g * copysignf(p, f);
    r = copysignf(d, f);
  }
}

__device__ __forceinline__ void slaev2f(float a, float b, float c,
                                        float& rt1, float& rt2, float& cs1, float& sn1) {
  float sm = a + c;
  float df = a - c;
  float adf = fabsf(df);
  float tb = b + b;
  float ab = fabsf(tb);
  float acmx, acmn;
  if (fabsf(a) > fabsf(c)) { acmx = a; acmn = c; } else { acmx = c; acmn = a; }
  float rt;
  if (adf > ab)      { float t = ab / adf; rt = adf * sqrtf(1.f + t * t); }
  else if (adf < ab) { float t = adf / ab; rt = ab * sqrtf(1.f + t * t); }
  else               { rt = ab * sqrtf(2.f); }
  int sgn1;
  if (sm < 0.f) {
    rt1 = 0.5f * (sm - rt); sgn1 = -1;
    rt2 = (acmx / rt1) * acmn - (b / rt1) * b;
  } else if (sm > 0.f) {
    rt1 = 0.5f * (sm + rt); sgn1 = 1;
    rt2 = (acmx / rt1) * acmn - (b / rt1) * b;
  } else {
    rt1 = 0.5f * rt; rt2 = -0.5f * rt; sgn1 = 1;
  }
  int sgn2; float cs;
  if (df >= 0.f) { cs = df + rt; sgn2 = 1; } else { cs = df - rt; sgn2 = -1; }
  float acs = fabsf(cs);
  if (acs > ab) {
    float ct = -tb / cs;
    sn1 = 1.f / sqrtf(1.f + ct * ct);
    cs1 = ct * sn1;
  } else {
    if (ab == 0.f) { cs1 = 1.f; sn1 = 0.f; }
    else {
      float tn = -cs / tb;
      cs1 = 1.f / sqrtf(1.f + tn * tn);
      sn1 = tn * cs1;
    }
  }
  if (sgn1 == sgn2) { float tn = cs1; cs1 = -sn1; sn1 = tn; }
}

// Column rotations on the scalarized 3x3 eigenvector matrix (z[row][col]).
#define ROT12(c, s) {                                         \
    float t_;                                                 \
    t_ = z01; z01 = (c) * t_ - (s) * z00; z00 = (s) * t_ + (c) * z00; \
    t_ = z11; z11 = (c) * t_ - (s) * z10; z10 = (s) * t_ + (c) * z10; \
    t_ = z21; z21 = (c) * t_ - (s) * z20; z20 = (s) * t_ + (c) * z20; }
#define ROT23(c, s) {                                         \
    float t_;                                                 \
    t_ = z02; z02 = (c) * t_ - (s) * z01; z01 = (s) * t_ + (c) * z01; \
    t_ = z12; z12 = (c) * t_ - (s) * z11; z11 = (s) * t_ + (c) * z11; \
    t_ = z22; z22 = (c) * t_ - (s) * z21; z21 = (s) * t_ + (c) * z21; }

// SSTEQR('I', n=3), fully scalarized: all state in VGPRs, zero scratch.
// Full implicit-shift QL step only fires at (l,m2,lend)=(1,3,3); QR at
// (3,1,1) — m2==l and m2==l±1 cases are peeled first. Op order identical
// to the reference array version.
__device__ __forceinline__ void ssteqr3_reg(
    float& d0, float& d1, float& d2, float& e0, float& e1,
    float& z00, float& z01, float& z02,
    float& z10, float& z11, float& z12,
    float& z20, float& z21, float& z22) {
  const float eps = 5.9604645e-8f;
  const float eps2 = eps * eps;
  const float safmin = 1.1754944e-38f;
  const int nmaxit = 90;
  int jtot = 0;
  int l1 = 1;
  for (int og = 0; og < 4; ++og) {
    if (l1 > 3) break;
    if (l1 == 2) e0 = 0.f;
    else if (l1 == 3) e1 = 0.f;
    int m = 3;
    if (l1 == 1) {
      float t = fabsf(e0);
      if (t == 0.f) m = 1;
      else if (t <= (sqrtf(fabsf(d0)) * sqrtf(fabsf(d1))) * eps) { e0 = 0.f; m = 1; }
      else {
        float t2 = fabsf(e1);
        if (t2 == 0.f) m = 2;
        else if (t2 <= (sqrtf(fabsf(d1)) * sqrtf(fabsf(d2))) * eps) { e1 = 0.f; m = 2; }
      }
    } else if (l1 == 2) {
      float t = fabsf(e1);
      if (t == 0.f) m = 2;
      else if (t <= (sqrtf(fabsf(d1)) * sqrtf(fabsf(d2))) * eps) { e1 = 0.f; m = 2; }
    }
    int l = l1, lend = m;
    l1 = m + 1;
    if (lend == l) continue;
    {
      float dlend = (lend == 1) ? d0 : ((lend == 2) ? d1 : d2);
      float dl = (l == 1) ? d0 : ((l == 2) ? d1 : d2);
      if (fabsf(dlend) < fabsf(dl)) { int t = lend; lend = l; l = t; }
    }
    if (lend > l) {
      // ---- QL iteration ----
      for (int it = 0; it < 128; ++it) {
        int m2 = lend;
        if (l != lend) {
          for (int mm = l; mm <= lend - 1; ++mm) {
            float em  = (mm == 1) ? e0 : e1;
            float dm1 = (mm == 1) ? d0 : d1;
            float dm  = (mm == 1) ? d1 : d2;
            float tst = em * em;
            if (tst <= (eps2 * fabsf(dm1)) * fabsf(dm) + safmin) { m2 = mm; break; }
          }
        }
        if (m2 < lend) { if (m2 == 1) e0 = 0.f; else e1 = 0.f; }
        float p = (l == 1) ? d0 : ((l == 2) ? d1 : d2);
        if (m2 == l) { l += 1; if (l <= lend) continue; break; }
        if (m2 == l + 1) {
          float rt1, rt2, c, s;
          if (l == 1) {
            slaev2f(d0, e0, d1, rt1, rt2, c, s);
            ROT12(c, s)
            d0 = rt1; d1 = rt2; e0 = 0.f;
          } else {
            slaev2f(d1, e1, d2, rt1, rt2, c, s);
            ROT23(c, s)
            d1 = rt1; d2 = rt2; e1 = 0.f;
          }
          l += 2; if (l <= lend) continue; break;
        }
        if (jtot == nmaxit) break;
        jtot++;
        // full QL step: l=1, m2=3, lend=3
        float g = (d1 - p) / (2.f * e0);
        float r = lapy2f(g, 1.f);
        g = d2 - p + e0 / (g + copysignf(r, g));
        float s = 1.f, c = 1.f;
        p = 0.f;
        float c0, s0n, c1, s1n;
        {  // i = 2
          float f = s * e1;
          float bb = c * e1;
          slartgf(g, f, c, s, r);
          g = d2 - p;
          r = (d1 - g) * s + 2.f * c * bb;
          p = s * r;
          d2 = g + p;
          g = c * r - bb;
          c1 = c; s1n = -s;
        }
        {  // i = 1
          float f = s * e0;
          float bb = c * e0;
          slartgf(g, f, c, s, r);
          e1 = r;
          g = d1 - p;
          r = (d0 - g) * s + 2.f * c * bb;
          p = s * r;
          d1 = g + p;
          g = c * r - bb;
          c0 = c; s0n = -s;
        }
        ROT23(c1, s1n)
        ROT12(c0, s0n)
        d0 = d0 - p;
        e0 = g;
      }
    } else {
      // ---- QR iteration ----
      for (int it = 0; it < 128; ++it) {
        int m2 = lend;
        if (l != lend) {
          for (int mm = l; mm >= lend + 1; --mm) {
            float em  = (mm == 3) ? e1 : e0;
            float dm1 = (mm == 3) ? d2 : d1;
            float dm2 = (mm == 3) ? d1 : d0;
            float tst = em * em;
            if (tst <= (eps2 * fabsf(dm1)) * fabsf(dm2) + safmin) { m2 = mm; break; }
          }
        }
        if (m2 > lend) { if (m2 == 3) e1 = 0.f; else e0 = 0.f; }
        float p = (l == 1) ? d0 : ((l == 2) ? d1 : d2);
        if (m2 == l) { l -= 1; if (l >= lend) continue; break; }
        if (m2 == l - 1) {
          float rt1, rt2, c, s;
          if (l == 2) {
            slaev2f(d0, e0, d1, rt1, rt2, c, s);
            ROT12(c, s)
            d0 = rt1; d1 = rt2; e0 = 0.f;
          } else {
            slaev2f(d1, e1, d2, rt1, rt2, c, s);
            ROT23(c, s)
            d1 = rt1; d2 = rt2; e1 = 0.f;
          }
          l -= 2; if (l >= lend) continue; break;
        }
        if (jtot == nmaxit) break;
        jtot++;
        // full QR step: l=3, m2=1, lend=1
        float g = (d1 - p) / (2.f * e1);
        float r = lapy2f(g, 1.f);
        g = d0 - p + e1 / (g + copysignf(r, g));
        float s = 1.f, c = 1.f;
        p = 0.f;
        float c0, s0p, c1, s1p;
        {  // i = 1
          float f = s * e0;
          float bb = c * e0;
          slartgf(g, f, c, s, r);
          g = d0 - p;
          r = (d1 - g) * s + 2.f * c * bb;
          p = s * r;
          d0 = g + p;
          g = c * r - bb;
          c0 = c; s0p = s;
        }
        {  // i = 2
          float f = s * e1;
          float bb = c * e1;
          slartgf(g, f, c, s, r);
          e0 = r;
          g = d1 - p;
          r = (d2 - g) * s + 2.f * c * bb;
          p = s * r;
          d1 = g + p;
          g = c * r - bb;
          c1 = c; s1p = s;
        }
        ROT12(c0, s0p)
        ROT23(c1, s1p)
        d2 = d2 - p;
        e1 = g;
      }
    }
  }
  // ascending eigenvalue selection sort with column swaps
  {
    int k = 1; float p = d0;
    if (d1 < p) { k = 2; p = d1; }
    if (d2 < p) { k = 3; p = d2; }
    if (k == 2) {
      d1 = d0; d0 = p;
      float t;
      t = z00; z00 = z01; z01 = t;
      t = z10; z10 = z11; z11 = t;
      t = z20; z20 = z21; z21 = t;
    } else if (k == 3) {
      d2 = d0; d0 = p;
      float t;
      t = z00; z00 = z02; z02 = t;
      t = z10; z10 = z12; z12 = t;
      t = z20; z20 = z22; z22 = t;
    }
    k = 2; p = d1;
    if (d2 < p) { k = 3; p = d2; }
    if (k == 3) {
      d2 = d1; d1 = p;
      float t;
      t = z01; z01 = z02; z02 = t;
      t = z11; z11 = z12; z12 = t;
      t = z21; z21 = z22; z22 = t;
    }
  }
}

// ---------------- Kernel 1: KNN (wave-per-point) + eigh + SoA emit ----------------
// 512 blocks x 256 threads; wave wv handles point 4b+wv. KNN math identical
// to the R4-passing kernel. After __syncthreads, threads 0..3 run the
// scalarized cov+eigh for the block's 4 points. Also emits SoA copies of
// pts and normals for kernel 2's coalesced loads.

__global__ __launch_bounds__(256) void knn_normals_kernel(
    const float* __restrict__ pts,
    float* __restrict__ pxa, float* __restrict__ pya, float* __restrict__ pza,
    float* __restrict__ nxa, float* __restrict__ nya, float* __restrict__ nza) {
  __shared__ int knn_lds[4][KNN];
  const int tid = threadIdx.x;
  const int lane = tid & 63;
  const int wv = tid >> 6;

  {
    const int p = 4 * blockIdx.x + wv;
    float px = pts[3 * p], py = pts[3 * p + 1], pz = pts[3 * p + 2];
    if (lane == 0) { pxa[p] = px; pya[p] = py; pza[p] = pz; }

    unsigned long long k0[8], k1[8], k2[8], k3[8];
#define DIST(g, arr)                                                      \
    {                                                                     \
      _Pragma("unroll")                                                   \
      for (int t = 0; t < 8; ++t) {                                       \
        int j = ((g) * 8 + t) * 64 + lane;                                \
        float dx = px - pts[3 * j];                                       \
        float dy = py - pts[3 * j + 1];                                   \
        float dz = pz - pts[3 * j + 2];                                   \
        float sq = dx * dx;                                               \
        sq = sq + dy * dy;                                                \
        sq = sq + dz * dz;                                                \
        arr[t] = (((unsigned long long)__float_as_uint(sq)) << 32) |      \
                 (unsigned int)j;                                         \
      }                                                                   \
    }
    DIST(0, k0) DIST(1, k1) DIST(2, k2) DIST(3, k3)
#undef DIST

#define CE(arr, a, b)                                                     \
    {                                                                     \
      unsigned long long lo = arr[a] < arr[b] ? arr[a] : arr[b];          \
      unsigned long long hi = arr[a] < arr[b] ? arr[b] : arr[a];          \
      arr[a] = lo; arr[b] = hi;                                           \
    }
#define SORT8(arr)                                                        \
    CE(arr, 0, 1) CE(arr, 2, 3) CE(arr, 4, 5) CE(arr, 6, 7)               \
    CE(arr, 0, 2) CE(arr, 1, 3) CE(arr, 4, 6) CE(arr, 5, 7)               \
    CE(arr, 1, 2) CE(arr, 5, 6) CE(arr, 0, 4) CE(arr, 3, 7)               \
    CE(arr, 1, 5) CE(arr, 2, 6)                                           \
    CE(arr, 1, 4) CE(arr, 3, 6)                                           \
    CE(arr, 2, 4) CE(arr, 3, 5)                                           \
    CE(arr, 3, 4)
    SORT8(k0) SORT8(k1) SORT8(k2) SORT8(k3)
#undef SORT8
#undef CE

#define POP(arr)                                                          \
    {                                                                     \
      _Pragma("unroll")                                                   \
      for (int q = 0; q < 7; ++q) arr[q] = arr[q + 1];                    \
      arr[7] = 0xFFFFFFFFFFFFFFFFULL;                                     \
    }
    for (int r = 0; r < KNN + 1; ++r) {
      unsigned long long h01 = k0[0] < k1[0] ? k0[0] : k1[0];
      unsigned long long h23 = k2[0] < k3[0] ? k2[0] : k3[0];
      unsigned long long h = h01 < h23 ? h01 : h23;
      unsigned long long m = h;
#pragma unroll
      for (int off = 32; off > 0; off >>= 1) {
        unsigned long long o = __shfl_xor(m, off, 64);
        m = (o < m) ? o : m;
      }
      if (r > 0 && lane == 0) knn_lds[wv][r - 1] = (int)(unsigned int)m;
      if (h == m) {  // unique winner (index bits make keys distinct)
        if (k0[0] == m)      { POP(k0) }
        else if (k1[0] == m) { POP(k1) }
        else if (k2[0] == m) { POP(k2) }
        else                 { POP(k3) }
      }
    }
#undef POP
  }
  __syncthreads();

  // ---- covariance + eigh for the block's 4 points (threads 0..3) ----
  if (tid < 4) {
    const int p = 4 * blockIdx.x + tid;
    float nx[KNN], ny[KNN], nz[KNN];
    float sx = 0.f, sy = 0.f, sz = 0.f;
#pragma unroll
    for (int t = 0; t < KNN; ++t) {
      int j = knn_lds[tid][t];
      nx[t] = pts[3 * j]; ny[t] = pts[3 * j + 1]; nz[t] = pts[3 * j + 2];
      sx = sx + nx[t]; sy = sy + ny[t]; sz = sz + nz[t];
    }
    float mx = sx / 10.f, my = sy / 10.f, mz = sz / 10.f;
    float a11 = 0.f, a21 = 0.f, a31 = 0.f, a22 = 0.f, a32 = 0.f, a33 = 0.f;
#pragma unroll
    for (int t = 0; t < KNN; ++t) {
      float cx = nx[t] - mx, cy = ny[t] - my, cz = nz[t] - mz;
      a11 = a11 + cx * cx;
      a21 = a21 + cy * cx;
      a31 = a31 + cz * cx;
      a22 = a22 + cy * cy;
      a32 = a32 + cz * cy;
      a33 = a33 + cz * cz;
    }
    a11 = a11 / 10.f; a21 = a21 / 10.f; a31 = a31 / 10.f;
    a22 = a22 / 10.f; a32 = a32 / 10.f; a33 = a33 / 10.f;

    // SSYTD2 (uplo='L', n=3)
    float d0, d1, d2, e0, e1, tau1 = 0.f, v2 = 0.f;
    {
      float alpha = a21;
      float xnorm = fabsf(a31);
      if (xnorm == 0.f) {
        tau1 = 0.f; v2 = 0.f;
        d0 = a11; d1 = a22; d2 = a33; e0 = alpha; e1 = a32;
      } else {
        float beta = -copysignf(lapy2f(alpha, xnorm), alpha);
        tau1 = (beta - alpha) / beta;
        v2 = a31 * (1.f / (alpha - beta));  // DSCAL: reciprocal then multiply
        float y1 = tau1 * a22; y1 = y1 + tau1 * (a32 * v2);
        float y2 = tau1 * a32; y2 = y2 + (tau1 * v2) * a33;
        float dotv = y1; dotv = dotv + y2 * v2;
        float ac = -0.5f * tau1 * dotv;
        y1 = y1 + ac;
        y2 = y2 + ac * v2;
        float t1 = -y1, t2 = -1.f;
        a22 = (a22 + t1) + y1 * t2;
        a32 = (a32 + v2 * t1) + y2 * t2;
        float t1b = -y2, t2b = -v2;
        a33 = (a33 + v2 * t1b) + y2 * t2b;
        d0 = a11; d1 = a22; d2 = a33; e0 = beta; e1 = a32;
      }
    }
    float z00 = 1.f, z01 = 0.f, z02 = 0.f;
    float z10 = 0.f, z11 = 1.f, z12 = 0.f;
    float z20 = 0.f, z21 = 0.f, z22 = 1.f;
    ssteqr3_reg(d0, d1, d2, e0, e1,
                z00, z01, z02, z10, z11, z12, z20, z21, z22);
    if (tau1 != 0.f) {
      float w = tau1 * (z10 + v2 * z20);
      z10 = z10 - w;
      z20 = z20 - v2 * w;
    }
    nxa[p] = z00;
    nya[p] = z10;
    nza[p] = z20;
  }
}

// ---------------- Kernel 2: PPF, one WAVE per point ----------------
// 512 blocks x 256 threads; wave wv handles point i = 4b+wv. 32 j-iters per
// lane on coalesced SoA loads; shuffle-butterfly reduce (no LDS, no
// barriers); float4 epilogue (4 outputs per lane).

__device__ __forceinline__ float atan2_pos(float y, float x) {
#pragma clang fp contract(fast)
  // y >= 0; returns atan2(y, x) in [0, pi]; |err| <= 1e-5 rad
  float axx = fabsf(x);
  float mn = fminf(axx, y), mx = fmaxf(axx, y);
  float a = mn * __builtin_amdgcn_rcpf(mx);
  a = (mx == 0.f) ? 0.f : a;
  float s = a * a;
  float r = a * (0.9998660f +
           s * (-0.3302995f +
           s * (0.1801410f +
           s * (-0.0851330f +
           s * 0.0208351f))));
  r = (y > axx) ? 1.57079632679f - r : r;
  r = (x < 0.f) ? 3.14159265359f - r : r;
  return r;
}

__device__ __forceinline__ float angle3(float ax, float ay, float az,
                                        float bx, float by, float bz) {
#pragma clang fp contract(fast)
  float cx = ay * bz - az * by;
  float cy = az * bx - ax * bz;
  float cz = ax * by - ay * bx;
  float sq = cx * cx + cy * cy + cz * cz;
  float dot = ax * bx + ay * by + az * bz;
  return atan2_pos(sqrtf(sq), dot);
}

__global__ __launch_bounds__(256) void ppf_kernel(
    const float* __restrict__ pxa, const float* __restrict__ pya,
    const float* __restrict__ pza, const float* __restrict__ nxa,
    const float* __restrict__ nya, const float* __restrict__ nza,
    const float* __restrict__ Wm, const float* __restrict__ bias,
    float* __restrict__ out) {
#pragma clang fp contract(fast)
  const int tid = threadIdx.x;
  const int lane = tid & 63;
  const int wv = tid >> 6;
  const int i = 4 * blockIdx.x + wv;

  float pxi = pxa[i], pyi = pya[i], pzi = pza[i];
  float ax = nxa[i], ay = nya[i], az = nza[i];

  float s0 = 0.f, s1 = 0.f, s2 = 0.f, s3 = 0.f;
#pragma unroll 4
  for (int it = 0; it < NPTS / 64; ++it) {
    int j = it * 64 + lane;
    float dx = pxi - pxa[j];
    float dy = pyi - pya[j];
    float dz = pzi - pza[j];
    float bx = nxa[j], by = nya[j], bz = nza[j];
    float sq = dx * dx + dy * dy + dz * dz;
    s0 += sqrtf(sq);
    s1 += angle3(ax, ay, az, dx, dy, dz);
    s2 += angle3(bx, by, bz, dx, dy, dz);
    s3 += angle3(ax, ay, az, bx, by, bz);
  }

  // wave butterfly reduce: all lanes end with the full sums
#pragma unroll
  for (int off = 1; off < 64; off <<= 1) {
    s0 += __shfl_xor(s0, off, 64);
    s1 += __shfl_xor(s1, off, 64);
    s2 += __shfl_xor(s2, off, 64);
    s3 += __shfl_xor(s3, off, 64);
  }
  const float inv = 1.f / 2048.f;  // power of two: identical to /2048
  float f0 = s0 * inv, f1 = s1 * inv, f2 = s2 * inv, f3 = s3 * inv;

  // epilogue: 4 outputs per lane via float4 (W rows are exactly float4)
  const float4* W4 = (const float4*)Wm;
  const float4* b4 = (const float4*)bias;
  float4 bb = b4[lane];
  float4 w0 = W4[4 * lane + 0];
  float4 w1 = W4[4 * lane + 1];
  float4 w2 = W4[4 * lane + 2];
  float4 w3 = W4[4 * lane + 3];
  float4 r;
  r.x = (((f0 * w0.x + f1 * w0.y) + f2 * w0.z) + f3 * w0.w) + bb.x;
  r.y = (((f0 * w1.x + f1 * w1.y) + f2 * w1.z) + f3 * w1.w) + bb.y;
  r.z = (((f0 * w2.x + f1 * w2.y) + f2 * w2.z) + f3 * w2.w) + bb.z;
  r.w = (((f0 * w3.x + f1 * w3.y) + f2 * w3.z) + f3 * w3.w) + bb.w;
  ((float4*)(out + (size_t)i * NOUT))[lane] = r;
}

// ---------------- launcher ----------------

extern "C" void kernel_launch(void* const* d_in, const int* in_sizes, int n_in,
                              void* d_out, int out_size, void* d_ws, size_t ws_size,
                              hipStream_t stream) {
  const float* pts = (const float*)d_in[0];   // (1,2048,3) fp32
  const float* Wm  = (const float*)d_in[1];   // (256,4) fp32
  const float* bs  = (const float*)d_in[2];   // (256,) fp32
  float* out = (float*)d_out;                 // (1,2048,256) fp32

  float* pxa = (float*)d_ws;                  // 6 SoA arrays of 2048 floats
  float* pya = pxa + NPTS;
  float* pza = pya + NPTS;
  float* nxa = pza + NPTS;
  float* nya = nxa + NPTS;
  float* nza = nya + NPTS;

  knn_normals_kernel<<<NPTS / 4, 256, 0, stream>>>(pts, pxa, pya, pza, nxa, nya, nza);
  ppf_kernel<<<NPTS / 4, 256, 0, stream>>>(pxa, pya, pza, nxa, nya, nza, Wm, bs, out);
}